// Round 2
// baseline (1668.395 us; speedup 1.0000x reference)
//
#include <hip/hip_runtime.h>
#include <math.h>

#define NPT 8192
#define CCH 128
#define KK  128

__device__ __forceinline__ unsigned f2key(float f) {
  unsigned u = __float_as_uint(f);
  return u ^ ((u & 0x80000000u) ? 0xFFFFFFFFu : 0x80000000u);
}
__device__ __forceinline__ float key2f(unsigned k) {
  unsigned u = (k & 0x80000000u) ? (k ^ 0x80000000u) : ~k;
  return __uint_as_float(u);
}

// ---------------- stats zero ----------------
__global__ void k_zero(double* s) {
  int t = threadIdx.x;
  if (t < 48) s[t] = 0.0;
}

// ---------------- corr GEMM (fp32, slab) ----------------
// corr[n][m] = (sum_c A[c][n]*B[c][m]) / sqrt(128), slab rows [row0, row0+SR)
__global__ __launch_bounds__(256) void k_gemm(const float* __restrict__ A,
                                              const float* __restrict__ B,
                                              float* __restrict__ slab, int row0) {
  __shared__ float a_s[CCH * 16];  // [c][r]
  int tid = threadIdx.x;
  int rbase = row0 + blockIdx.y * 16;
  for (int i = tid; i < CCH * 16; i += 256) {
    int c = i >> 4, r = i & 15;
    a_s[i] = A[(size_t)c * NPT + rbase + r];
  }
  __syncthreads();
  int mb = blockIdx.x * 2048;
  for (int chunk = 0; chunk < 2; ++chunk) {
    int m = mb + chunk * 1024 + tid * 4;
    float acc[16][4];
#pragma unroll
    for (int r = 0; r < 16; ++r) { acc[r][0] = acc[r][1] = acc[r][2] = acc[r][3] = 0.f; }
#pragma unroll 4
    for (int c = 0; c < CCH; ++c) {
      float4 bv = *(const float4*)(B + (size_t)c * NPT + m);
#pragma unroll
      for (int r = 0; r < 16; ++r) {
        float av = a_s[c * 16 + r];
        acc[r][0] += av * bv.x; acc[r][1] += av * bv.y;
        acc[r][2] += av * bv.z; acc[r][3] += av * bv.w;
      }
    }
    const float sc = 0.08838834764831845f;  // 1/sqrt(128)
    int rl = blockIdx.y * 16;
#pragma unroll
    for (int r = 0; r < 16; ++r) {
      float4 o = make_float4(acc[r][0] * sc, acc[r][1] * sc, acc[r][2] * sc, acc[r][3] * sc);
      *(float4*)(slab + (size_t)(rl + r) * NPT + m) = o;
    }
  }
}

// ---------------- exact per-row top-128 via 4-pass radix select ----------------
__global__ __launch_bounds__(256) void k_select(const float* __restrict__ slab, int row0,
                                                float* __restrict__ tcorr, int* __restrict__ tidx) {
  __shared__ unsigned keys[NPT];
  __shared__ unsigned hist[256];
  __shared__ unsigned sh_prefix;
  __shared__ int sh_kneed;
  __shared__ int sh_cnt;
  int tid = threadIdx.x;
  int rl = blockIdx.x;
  const float* rowp = slab + (size_t)rl * NPT;
  for (int i = tid; i < NPT; i += 256) keys[i] = f2key(rowp[i]);
  if (tid == 0) { sh_prefix = 0u; sh_kneed = KK; sh_cnt = 0; }
  __syncthreads();
  for (int pass = 0; pass < 4; ++pass) {
    int shift = 24 - 8 * pass;
    hist[tid] = 0u;
    __syncthreads();
    unsigned pref = sh_prefix;
    unsigned maskhi = (pass == 0) ? 0u : (0xFFFFFFFFu << (shift + 8));
    for (int i = tid; i < NPT; i += 256) {
      unsigned k = keys[i];
      if ((k & maskhi) == (pref & maskhi)) atomicAdd(&hist[(k >> shift) & 255u], 1u);
    }
    __syncthreads();
    if (tid == 0) {
      unsigned cum = 0;
      for (int b = 255; b >= 0; --b) {
        unsigned h = hist[b];
        if (cum + h >= (unsigned)sh_kneed) {
          sh_kneed -= (int)cum;
          sh_prefix = pref | (((unsigned)b) << shift);
          break;
        }
        cum += h;
      }
    }
    __syncthreads();
  }
  unsigned T = sh_prefix;
  int row = row0 + rl;
  for (int i = tid; i < NPT; i += 256) {
    unsigned k = keys[i];
    if (k > T) {
      int pos = atomicAdd(&sh_cnt, 1);
      tcorr[(size_t)row * KK + pos] = key2f(k);
      tidx[(size_t)row * KK + pos] = i;
    }
  }
  __syncthreads();
  for (int i = tid; i < NPT; i += 256) {
    unsigned k = keys[i];
    if (k == T) {
      int pos = atomicAdd(&sh_cnt, 1);
      if (pos < KK) {
        tcorr[(size_t)row * KK + pos] = key2f(k);
        tidx[(size_t)row * KK + pos] = i;
      }
    }
  }
}

// ---------------- per-point voxel/coarse/knn geometry ----------------
__global__ __launch_bounds__(128) void k_point(const float* __restrict__ tcorr,
                                               const int* __restrict__ tidx,
                                               const float* __restrict__ xyz2,
                                               const float* __restrict__ coords,
                                               float* __restrict__ feats,
                                               float* __restrict__ vox_in,
                                               float* __restrict__ knn_in) {
  __shared__ float px[128], py[128], pz[128], dd[128];
  __shared__ float cadd[81], ccnt[81];
  __shared__ unsigned long long cmax[27];
  __shared__ unsigned long long gmax;  // block-wide argmax of corr (sorted position 0)
  __shared__ float mvx[27], mvy[27], mvz[27];
  __shared__ int oobs[27];
  __shared__ float vadd[28];
  __shared__ int vcnt[28];
  int n = blockIdx.x, t = threadIdx.x;
  float v = tcorr[(size_t)n * KK + t];
  int idx = tidx[(size_t)n * KK + t];
  float p0 = xyz2[idx * 3 + 0], p1 = xyz2[idx * 3 + 1], p2 = xyz2[idx * 3 + 2];
  float c0 = coords[n * 3 + 0], c1 = coords[n * 3 + 1], c2 = coords[n * 3 + 2];
  px[t] = p0; py[t] = p1; pz[t] = p2;
  float dx = p0 - c0, dy = p1 - c1, dz = p2 - c2;
  dd[t] = dx * dx + dy * dy + dz * dz;
  if (t < 81) { cadd[t] = 0.f; ccnt[t] = 0.f; }
  if (t < 27) cmax[t] = 0ULL;
  if (t < 28) { vadd[t] = 0.f; vcnt[t] = 0; }
  if (t == 0) gmax = 0ULL;
  __syncthreads();
  // multi-level 27-cube average pooling (r = 0.25, 0.5, 1.0)
#pragma unroll
  for (int lvl = 0; lvl < 3; ++lvl) {
    float rinv = (lvl == 0) ? 4.f : (lvl == 1) ? 2.f : 1.f;
    float d0 = rintf(dx * rinv), d1 = rintf(dy * rinv), d2 = rintf(dz * rinv);
    if (fabsf(d0) <= 1.f && fabsf(d1) <= 1.f && fabsf(d2) <= 1.f) {
      int cube = (int)(d0 + 1.f) * 9 + (int)(d1 + 1.f) * 3 + (int)(d2 + 1.f);
      atomicAdd(&cadd[lvl * 27 + cube], v);
      atomicAdd(&ccnt[lvl * 27 + cube], 1.f);
    }
  }
  unsigned long long pk = (((unsigned long long)f2key(v)) << 32) | (unsigned)t;
  atomicMax(&gmax, pk);
  // coarse bins (R = 4): per-bin argmax of corr via packed u64 atomicMax
  {
    float d0 = rintf(dx * 0.25f), d1 = rintf(dy * 0.25f), d2 = rintf(dz * 0.25f);
    if (fabsf(d0) <= 1.5f && fabsf(d1) <= 1.5f && fabsf(d2) <= 1.5f) {
      int bin = (int)(d0 + 1.f) * 9 + (int)(d1 + 1.f) * 3 + (int)(d2 + 1.f);
      atomicMax(&cmax[bin], pk);
    }
  }
  __syncthreads();
  if (t < 27) {
    unsigned long long pkb = cmax[t];
    unsigned hi = (unsigned)(pkb >> 32);
    int ob = (hi <= 0x80000000u) ? 1 : 0;  // empty bin or max corr <= 0
    // oob fallback: reference center_idx=0 == sorted position 0 == global argmax corr
    int ki = ob ? (int)(gmax & 0xFFFFFFFFULL) : (int)(pkb & 0xFFFFFFFFULL);
    float ccx = px[ki], ccy = py[ki], ccz = pz[ki];
    float bx = (float)(t / 9 - 1), by = (float)((t / 3) % 3 - 1), bz = (float)(t % 3 - 1);
    float vk0 = c0 + bx * 4.f, vk1 = c1 + by * 4.f, vk2 = c2 + bz * 4.f;
    float m0 = fminf(fmaxf(ccx - vk0, -1.f), 1.f) + vk0;
    float m1 = fminf(fmaxf(ccy - vk1, -1.f), 1.f) + vk1;
    float m2 = fminf(fmaxf(ccz - vk2, -1.f), 1.f) + vk2;
    mvx[t] = m0; mvy[t] = m1; mvz[t] = m2; oobs[t] = ob;
    float* vp = vox_in + ((size_t)n * 27 + t) * 4;
    vp[1] = m0; vp[2] = m1; vp[3] = m2;
  }
  __syncthreads();
  // idx_scatter: later bin overwrites, rep = |p - mv| <= r/2 per dim (r=2)
  int is = 27;
#pragma unroll 1
  for (int b = 0; b < 27; ++b) {
    if (!oobs[b] && fabsf(p0 - mvx[b]) <= 1.f && fabsf(p1 - mvy[b]) <= 1.f &&
        fabsf(p2 - mvz[b]) <= 1.f)
      is = b;
  }
  atomicAdd(&vadd[is], v);
  atomicAdd(&vcnt[is], 1);
  __syncthreads();
  if (t < 27) {
    float cnt = fmaxf((float)vcnt[t], 1.f);
    vox_in[((size_t)n * 27 + t) * 4 + 0] = vadd[t] / cnt;
  }
  if (t < 81) {
    float cnt = fminf(fmaxf(ccnt[t], 1.f), 8192.f);
    feats[(size_t)t * NPT + n] = cadd[t] / cnt;
  }
  // exact 32-NN among the K=128 by squared distance, rank = position (ties by index)
  float d = dd[t];
  int rank = 0;
  for (int j = 0; j < 128; ++j) {
    float dj = dd[j];
    rank += (dj < d || (dj == d && j < t)) ? 1 : 0;
  }
  if (rank < 32) {
    float* kp = knn_in + ((size_t)n * 32 + rank) * 4;
    *(float4*)kp = make_float4(v, dx, dy, dz);
  }
}

// ---------------- vox branch: conv(4->32) GN stats ----------------
__global__ __launch_bounds__(256) void k_vox_stats(const float* __restrict__ vox_in,
                                                   const float* __restrict__ w1,
                                                   const float* __restrict__ b1,
                                                   double* __restrict__ stats) {
  float gs[8], gq[8];
#pragma unroll
  for (int g = 0; g < 8; ++g) { gs[g] = 0.f; gq[g] = 0.f; }
  for (int s = blockIdx.x * 256 + threadIdx.x; s < NPT * 27; s += gridDim.x * 256) {
    float4 in = *(const float4*)(vox_in + (size_t)s * 4);
#pragma unroll
    for (int oc = 0; oc < 32; ++oc) {
      float4 w = *(const float4*)(w1 + oc * 4);
      float h = w.x * in.x + w.y * in.y + w.z * in.z + w.w * in.w + b1[oc];
      gs[oc >> 2] += h; gq[oc >> 2] += h * h;
    }
  }
  __shared__ float ls[8], lq[8];
  if (threadIdx.x < 8) { ls[threadIdx.x] = 0.f; lq[threadIdx.x] = 0.f; }
  __syncthreads();
#pragma unroll
  for (int g = 0; g < 8; ++g) { atomicAdd(&ls[g], gs[g]); atomicAdd(&lq[g], gq[g]); }
  __syncthreads();
  if (threadIdx.x < 8) {
    atomicAdd(&stats[threadIdx.x * 2 + 0], (double)ls[threadIdx.x]);
    atomicAdd(&stats[threadIdx.x * 2 + 1], (double)lq[threadIdx.x]);
  }
}

// ---------------- knn branch: conv(4->64) GN stats ----------------
__global__ __launch_bounds__(256) void k_knn_stats(const float* __restrict__ knn_in,
                                                   const float* __restrict__ w1,
                                                   const float* __restrict__ b1,
                                                   double* __restrict__ stats) {
  float gs[8], gq[8];
#pragma unroll
  for (int g = 0; g < 8; ++g) { gs[g] = 0.f; gq[g] = 0.f; }
  for (int s = blockIdx.x * 256 + threadIdx.x; s < NPT * 32; s += gridDim.x * 256) {
    float4 in = *(const float4*)(knn_in + (size_t)s * 4);
#pragma unroll
    for (int oc = 0; oc < 64; ++oc) {
      float4 w = *(const float4*)(w1 + oc * 4);
      float h = w.x * in.x + w.y * in.y + w.z * in.z + w.w * in.w + b1[oc];
      gs[oc >> 3] += h; gq[oc >> 3] += h * h;
    }
  }
  __shared__ float ls[8], lq[8];
  if (threadIdx.x < 8) { ls[threadIdx.x] = 0.f; lq[threadIdx.x] = 0.f; }
  __syncthreads();
#pragma unroll
  for (int g = 0; g < 8; ++g) { atomicAdd(&ls[g], gs[g]); atomicAdd(&lq[g], gq[g]); }
  __syncthreads();
  if (threadIdx.x < 8) {
    atomicAdd(&stats[threadIdx.x * 2 + 0], (double)ls[threadIdx.x]);
    atomicAdd(&stats[threadIdx.x * 2 + 1], (double)lq[threadIdx.x]);
  }
}

// ---------------- vox branch apply: GN+PReLU+conv(32->1) -> feats rows 81..107 ----------------
__global__ __launch_bounds__(256) void k_vox_apply(const float* __restrict__ vox_in,
                                                   const float* __restrict__ w1,
                                                   const float* __restrict__ b1,
                                                   const float* __restrict__ gamma,
                                                   const float* __restrict__ beta,
                                                   const float* __restrict__ pr,
                                                   const float* __restrict__ w2,
                                                   const float* __restrict__ b2,
                                                   const double* __restrict__ stats,
                                                   float* __restrict__ feats) {
  int s = blockIdx.x * 256 + threadIdx.x;
  if (s >= NPT * 27) return;
  float mean[8], rstd[8];
  const double cntd = 4.0 * 8192.0 * 27.0;
#pragma unroll
  for (int g = 0; g < 8; ++g) {
    double m = stats[2 * g] / cntd;
    double var = stats[2 * g + 1] / cntd - m * m;
    mean[g] = (float)m;
    rstd[g] = (float)(1.0 / sqrt(var + 1e-5));
  }
  float a = pr[0];
  float4 in = *(const float4*)(vox_in + (size_t)s * 4);
  float out = b2[0];
#pragma unroll
  for (int oc = 0; oc < 32; ++oc) {
    float4 w = *(const float4*)(w1 + oc * 4);
    float h = w.x * in.x + w.y * in.y + w.z * in.z + w.w * in.w + b1[oc];
    int g = oc >> 2;
    float xn = (h - mean[g]) * rstd[g] * gamma[oc] + beta[oc];
    float y = (xn >= 0.f) ? xn : a * xn;
    out += w2[oc] * y;
  }
  int n = s / 27, bb = s - n * 27;
  feats[(size_t)(81 + bb) * NPT + n] = out;
}

// ---------------- knn apply: GN+PReLU, max over 32 -> kf (64 x N) ----------------
__global__ __launch_bounds__(256) void k_knn_max(const float* __restrict__ knn_in,
                                                 const float* __restrict__ w1,
                                                 const float* __restrict__ b1,
                                                 const float* __restrict__ gamma,
                                                 const float* __restrict__ beta,
                                                 const float* __restrict__ pr,
                                                 const double* __restrict__ stats,
                                                 float* __restrict__ kf) {
  int tid0 = blockIdx.x * 256 + threadIdx.x;
  int n = tid0 & (NPT - 1);
  int oc = tid0 >> 13;
  const double cntd = 8.0 * 8192.0 * 32.0;
  int g = oc >> 3;
  double md = stats[2 * g] / cntd;
  double var = stats[2 * g + 1] / cntd - md * md;
  float mean = (float)md, rstd = (float)(1.0 / sqrt(var + 1e-5));
  float4 w = *(const float4*)(w1 + oc * 4);
  float bb = b1[oc], ga = gamma[oc], be = beta[oc], a = pr[0];
  float mx = -INFINITY;
  for (int j = 0; j < 32; ++j) {
    float4 in = *(const float4*)(knn_in + ((size_t)n * 32 + j) * 4);
    float h = w.x * in.x + w.y * in.y + w.z * in.z + w.w * in.w + bb;
    float xn = (h - mean) * rstd * ga + be;
    float y = (xn >= 0.f) ? xn : a * xn;
    mx = fmaxf(mx, y);
  }
  kf[(size_t)oc * NPT + n] = mx;
}

// ---------------- out branch conv1 (108->128) + GN stats, h1 materialized ----------------
__global__ __launch_bounds__(256) void k_out1(const float* __restrict__ feats,
                                              const float* __restrict__ w1,
                                              const float* __restrict__ b1,
                                              float* __restrict__ h1,
                                              double* __restrict__ stats) {
  __shared__ float vf[108 * 64];
  __shared__ float ls[8], lq[8];
  int n0 = blockIdx.x * 64, tid = threadIdx.x;
  for (int i = tid; i < 108 * 64; i += 256) {
    int ch = i >> 6, nn = i & 63;
    vf[i] = feats[(size_t)ch * NPT + n0 + nn];
  }
  if (tid < 8) { ls[tid] = 0.f; lq[tid] = 0.f; }
  __syncthreads();
  int nn = tid & 63, oc0 = tid >> 6;
  float gs[8], gq[8];
#pragma unroll
  for (int g = 0; g < 8; ++g) { gs[g] = 0.f; gq[g] = 0.f; }
#pragma unroll
  for (int go = 0; go < 8; ++go) {
    for (int ii = 0; ii < 4; ++ii) {
      int oc = oc0 + 4 * (go * 4 + ii);  // oc>>4 == go
      float acc = b1[oc];
      for (int ic = 0; ic < 108; ++ic) acc += w1[oc * 108 + ic] * vf[ic * 64 + nn];
      h1[(size_t)oc * NPT + n0 + nn] = acc;
      gs[go] += acc; gq[go] += acc * acc;
    }
  }
#pragma unroll
  for (int g = 0; g < 8; ++g) { atomicAdd(&ls[g], gs[g]); atomicAdd(&lq[g], gq[g]); }
  __syncthreads();
  if (tid < 8) {
    atomicAdd(&stats[2 * tid + 0], (double)ls[tid]);
    atomicAdd(&stats[2 * tid + 1], (double)lq[tid]);
  }
}

// ---------------- final: GN+PReLU on h1, conv(128->64) + conv(64->64)(kf) + biases ----------------
__global__ __launch_bounds__(256) void k_final(const float* __restrict__ h1,
                                               const float* __restrict__ kf,
                                               const float* __restrict__ gamma,
                                               const float* __restrict__ beta,
                                               const float* __restrict__ pr,
                                               const float* __restrict__ w2,
                                               const float* __restrict__ b2,
                                               const float* __restrict__ kow,
                                               const float* __restrict__ kob,
                                               const double* __restrict__ stats,
                                               float* __restrict__ out) {
  __shared__ float hn[128 * 64];
  __shared__ float kft[64 * 64];
  __shared__ float s_mean[8], s_rstd[8];
  int n0 = blockIdx.x * 64, tid = threadIdx.x;
  if (tid < 8) {
    const double cntd = 16.0 * 8192.0;
    double m = stats[2 * tid] / cntd;
    double var = stats[2 * tid + 1] / cntd - m * m;
    s_mean[tid] = (float)m;
    s_rstd[tid] = (float)(1.0 / sqrt(var + 1e-5));
  }
  __syncthreads();
  float a = pr[0];
  for (int i = tid; i < 128 * 64; i += 256) {
    int ch = i >> 6, nn = i & 63;
    int g = ch >> 4;
    float x = h1[(size_t)ch * NPT + n0 + nn];
    float xn = (x - s_mean[g]) * s_rstd[g] * gamma[ch] + beta[ch];
    hn[i] = (xn >= 0.f) ? xn : a * xn;
  }
  for (int i = tid; i < 64 * 64; i += 256) {
    int ch = i >> 6, nn = i & 63;
    kft[i] = kf[(size_t)ch * NPT + n0 + nn];
  }
  __syncthreads();
  int nn = tid & 63, oc0 = tid >> 6;
#pragma unroll 1
  for (int i = 0; i < 16; ++i) {
    int oc = oc0 + 4 * i;
    float acc = b2[oc] + kob[oc];
    for (int ic = 0; ic < 128; ++ic) acc += w2[oc * 128 + ic] * hn[ic * 64 + nn];
    for (int ic = 0; ic < 64; ++ic) acc += kow[oc * 64 + ic] * kft[ic * 64 + nn];
    out[(size_t)oc * NPT + n0 + nn] = acc;
  }
}

extern "C" void kernel_launch(void* const* d_in, const int* in_sizes, int n_in,
                              void* d_out, int out_size, void* d_ws, size_t ws_size,
                              hipStream_t stream) {
  (void)in_sizes; (void)n_in; (void)out_size;
  const float* fmap1  = (const float*)d_in[0];
  const float* fmap2  = (const float*)d_in[1];
  const float* xyz2   = (const float*)d_in[2];
  const float* coords = (const float*)d_in[3];
  const float* out_w1 = (const float*)d_in[4];
  const float* out_b1 = (const float*)d_in[5];
  const float* out_g  = (const float*)d_in[6];
  const float* out_bt = (const float*)d_in[7];
  const float* out_pr = (const float*)d_in[8];
  const float* out_w2 = (const float*)d_in[9];
  const float* out_b2 = (const float*)d_in[10];
  const float* vox_w1 = (const float*)d_in[11];
  const float* vox_b1 = (const float*)d_in[12];
  const float* vox_g  = (const float*)d_in[13];
  const float* vox_bt = (const float*)d_in[14];
  const float* vox_pr = (const float*)d_in[15];
  const float* vox_w2 = (const float*)d_in[16];
  const float* vox_b2 = (const float*)d_in[17];
  const float* knn_w1 = (const float*)d_in[18];
  const float* knn_b1 = (const float*)d_in[19];
  const float* knn_g  = (const float*)d_in[20];
  const float* knn_bt = (const float*)d_in[21];
  const float* knn_pr = (const float*)d_in[22];
  const float* knn_ow = (const float*)d_in[23];
  const float* knn_ob = (const float*)d_in[24];

  float* ws = (float*)d_ws;
  const size_t nonslab = 6488512ull;  // floats: tcorr+tidx+feats+vox_in+knn_in+h1+kf
  int SR;
  if (ws_size >= (8388608ull + nonslab) * 4ull + 512ull) SR = 1024;
  else if (ws_size >= (4194304ull + nonslab) * 4ull + 512ull) SR = 512;
  else SR = 256;

  float* slab   = ws;
  float* tcorr  = slab + (size_t)SR * NPT;
  int*   tidx   = (int*)(tcorr + (size_t)NPT * KK);
  float* feats  = tcorr + (size_t)NPT * KK * 2;
  float* vox_in = feats + 108 * NPT;
  float* knn_in = vox_in + (size_t)NPT * 27 * 4;
  float* h1     = knn_in + (size_t)NPT * 32 * 4;
  float* kf     = h1 + 128 * NPT;
  double* stats = (double*)(kf + 64 * NPT);

  hipLaunchKernelGGL(k_zero, dim3(1), dim3(64), 0, stream, stats);
  int iters = NPT / SR;
  for (int s = 0; s < iters; ++s) {
    hipLaunchKernelGGL(k_gemm, dim3(4, SR / 16), dim3(256), 0, stream, fmap1, fmap2, slab, s * SR);
    hipLaunchKernelGGL(k_select, dim3(SR), dim3(256), 0, stream, slab, s * SR, tcorr, tidx);
  }
  hipLaunchKernelGGL(k_point, dim3(NPT), dim3(128), 0, stream, tcorr, tidx, xyz2, coords,
                     feats, vox_in, knn_in);
  hipLaunchKernelGGL(k_vox_stats, dim3(256), dim3(256), 0, stream, vox_in, vox_w1, vox_b1, stats);
  hipLaunchKernelGGL(k_knn_stats, dim3(512), dim3(256), 0, stream, knn_in, knn_w1, knn_b1, stats + 16);
  hipLaunchKernelGGL(k_vox_apply, dim3((NPT * 27 + 255) / 256), dim3(256), 0, stream, vox_in,
                     vox_w1, vox_b1, vox_g, vox_bt, vox_pr, vox_w2, vox_b2, stats, feats);
  hipLaunchKernelGGL(k_knn_max, dim3(64 * NPT / 256), dim3(256), 0, stream, knn_in, knn_w1,
                     knn_b1, knn_g, knn_bt, knn_pr, stats + 16, kf);
  hipLaunchKernelGGL(k_out1, dim3(NPT / 64), dim3(256), 0, stream, feats, out_w1, out_b1, h1,
                     stats + 32);
  hipLaunchKernelGGL(k_final, dim3(NPT / 64), dim3(256), 0, stream, h1, kf, out_g, out_bt,
                     out_pr, out_w2, out_b2, knn_ow, knn_ob, stats + 32, (float*)d_out);
}

// Round 3
// 986.926 us; speedup vs baseline: 1.6905x; 1.6905x over previous
//
#include <hip/hip_runtime.h>
#include <math.h>

#define NPT 8192
#define CCH 128
#define KK  128

__device__ __forceinline__ unsigned f2key(float f) {
  unsigned u = __float_as_uint(f);
  return u ^ ((u & 0x80000000u) ? 0xFFFFFFFFu : 0x80000000u);
}
__device__ __forceinline__ float key2f(unsigned k) {
  unsigned u = (k & 0x80000000u) ? (k ^ 0x80000000u) : ~k;
  return __uint_as_float(u);
}

// ---------------- stats zero ----------------
__global__ void k_zero(double* s) {
  int t = threadIdx.x;
  if (t < 48) s[t] = 0.0;
}

// ---------------- corr GEMM (fp32, slab) ----------------
// grid (16, SR/16): block = 16 rows x 512 cols, 4 blocks/CU target.
__global__ __launch_bounds__(256, 4) void k_gemm(const float* __restrict__ A,
                                                 const float* __restrict__ B,
                                                 float* __restrict__ slab, int row0) {
  __shared__ float a_s[CCH * 16];  // [c][r]
  int tid = threadIdx.x;
  int rbase = row0 + blockIdx.y * 16;
  for (int i = tid; i < CCH * 16; i += 256) {
    int c = i >> 4, r = i & 15;
    a_s[i] = A[(size_t)c * NPT + rbase + r];
  }
  __syncthreads();
  int m = blockIdx.x * 512 + tid * 2;
  float acc[16][2];
#pragma unroll
  for (int r = 0; r < 16; ++r) { acc[r][0] = 0.f; acc[r][1] = 0.f; }
#pragma unroll 4
  for (int c = 0; c < CCH; ++c) {
    float2 bv = *(const float2*)(B + (size_t)c * NPT + m);
    const float4* a4 = (const float4*)(a_s + c * 16);
#pragma unroll
    for (int q = 0; q < 4; ++q) {
      float4 av = a4[q];
      acc[q * 4 + 0][0] += av.x * bv.x; acc[q * 4 + 0][1] += av.x * bv.y;
      acc[q * 4 + 1][0] += av.y * bv.x; acc[q * 4 + 1][1] += av.y * bv.y;
      acc[q * 4 + 2][0] += av.z * bv.x; acc[q * 4 + 2][1] += av.z * bv.y;
      acc[q * 4 + 3][0] += av.w * bv.x; acc[q * 4 + 3][1] += av.w * bv.y;
    }
  }
  const float sc = 0.08838834764831845f;  // 1/sqrt(128)
  int rl = blockIdx.y * 16;
#pragma unroll
  for (int r = 0; r < 16; ++r) {
    float2 o; o.x = acc[r][0] * sc; o.y = acc[r][1] * sc;
    *(float2*)(slab + (size_t)(rl + r) * NPT + m) = o;
  }
}

// ---------------- exact per-row top-128: bitwise binary search on keys ----------------
// keys live in 32 VGPRs/thread; threshold found by 32 count-passes (no LDS atomics).
__global__ __launch_bounds__(256) void k_select(const float* __restrict__ slab, int row0,
                                                float* __restrict__ tcorr, int* __restrict__ tidx) {
  __shared__ int wcnt[4];
  __shared__ int sh_cnt;
  int tid = threadIdx.x, lane = tid & 63, wv = tid >> 6;
  const float* rowp = slab + (size_t)blockIdx.x * NPT;
  unsigned key[32];
#pragma unroll
  for (int j = 0; j < 32; ++j) key[j] = f2key(rowp[tid + j * 256]);
  if (tid == 0) sh_cnt = 0;
  unsigned P = 0;
  for (int b = 31; b >= 0; --b) {
    unsigned P1 = P | (1u << b);
    int c = 0;
#pragma unroll
    for (int j = 0; j < 32; ++j) c += (key[j] >= P1) ? 1 : 0;
    for (int off = 32; off; off >>= 1) c += __shfl_down(c, off);
    __syncthreads();  // protect wcnt from previous iteration's readers
    if (lane == 0) wcnt[wv] = c;
    __syncthreads();
    int tot = wcnt[0] + wcnt[1] + wcnt[2] + wcnt[3];
    if (tot >= KK) P = P1;
  }
  // P == the KK-th largest key. Emit strictly-greater, then ties up to KK.
  int row = row0 + blockIdx.x;
#pragma unroll
  for (int j = 0; j < 32; ++j) {
    if (key[j] > P) {
      int pos = atomicAdd(&sh_cnt, 1);
      tcorr[(size_t)row * KK + pos] = key2f(key[j]);
      tidx[(size_t)row * KK + pos] = tid + j * 256;
    }
  }
  __syncthreads();
#pragma unroll
  for (int j = 0; j < 32; ++j) {
    if (key[j] == P) {
      int pos = atomicAdd(&sh_cnt, 1);
      if (pos < KK) {
        tcorr[(size_t)row * KK + pos] = key2f(P);
        tidx[(size_t)row * KK + pos] = tid + j * 256;
      }
    }
  }
}

// ---------------- per-point voxel/coarse/knn geometry ----------------
__global__ __launch_bounds__(128) void k_point(const float* __restrict__ tcorr,
                                               const int* __restrict__ tidx,
                                               const float* __restrict__ xyz2,
                                               const float* __restrict__ coords,
                                               float* __restrict__ feats,
                                               float* __restrict__ vox_in,
                                               float* __restrict__ knn_in) {
  __shared__ float px[128], py[128], pz[128], dd[128];
  __shared__ float cadd[81], ccnt[81];
  __shared__ unsigned long long cmax[27];
  __shared__ unsigned long long gmax;  // block-wide argmax of corr (sorted position 0)
  __shared__ float mvx[27], mvy[27], mvz[27];
  __shared__ int oobs[27];
  __shared__ float vadd[28];
  __shared__ int vcnt[28];
  int n = blockIdx.x, t = threadIdx.x;
  float v = tcorr[(size_t)n * KK + t];
  int idx = tidx[(size_t)n * KK + t];
  float p0 = xyz2[idx * 3 + 0], p1 = xyz2[idx * 3 + 1], p2 = xyz2[idx * 3 + 2];
  float c0 = coords[n * 3 + 0], c1 = coords[n * 3 + 1], c2 = coords[n * 3 + 2];
  px[t] = p0; py[t] = p1; pz[t] = p2;
  float dx = p0 - c0, dy = p1 - c1, dz = p2 - c2;
  dd[t] = dx * dx + dy * dy + dz * dz;
  if (t < 81) { cadd[t] = 0.f; ccnt[t] = 0.f; }
  if (t < 27) cmax[t] = 0ULL;
  if (t < 28) { vadd[t] = 0.f; vcnt[t] = 0; }
  if (t == 0) gmax = 0ULL;
  __syncthreads();
  // multi-level 27-cube average pooling (r = 0.25, 0.5, 1.0)
#pragma unroll
  for (int lvl = 0; lvl < 3; ++lvl) {
    float rinv = (lvl == 0) ? 4.f : (lvl == 1) ? 2.f : 1.f;
    float d0 = rintf(dx * rinv), d1 = rintf(dy * rinv), d2 = rintf(dz * rinv);
    if (fabsf(d0) <= 1.f && fabsf(d1) <= 1.f && fabsf(d2) <= 1.f) {
      int cube = (int)(d0 + 1.f) * 9 + (int)(d1 + 1.f) * 3 + (int)(d2 + 1.f);
      atomicAdd(&cadd[lvl * 27 + cube], v);
      atomicAdd(&ccnt[lvl * 27 + cube], 1.f);
    }
  }
  unsigned long long pk = (((unsigned long long)f2key(v)) << 32) | (unsigned)t;
  atomicMax(&gmax, pk);
  // coarse bins (R = 4): per-bin argmax of corr via packed u64 atomicMax
  {
    float d0 = rintf(dx * 0.25f), d1 = rintf(dy * 0.25f), d2 = rintf(dz * 0.25f);
    if (fabsf(d0) <= 1.5f && fabsf(d1) <= 1.5f && fabsf(d2) <= 1.5f) {
      int bin = (int)(d0 + 1.f) * 9 + (int)(d1 + 1.f) * 3 + (int)(d2 + 1.f);
      atomicMax(&cmax[bin], pk);
    }
  }
  __syncthreads();
  if (t < 27) {
    unsigned long long pkb = cmax[t];
    unsigned hi = (unsigned)(pkb >> 32);
    int ob = (hi <= 0x80000000u) ? 1 : 0;  // empty bin or max corr <= 0
    // oob fallback: reference center_idx=0 == sorted position 0 == global argmax corr
    int ki = ob ? (int)(gmax & 0xFFFFFFFFULL) : (int)(pkb & 0xFFFFFFFFULL);
    float ccx = px[ki], ccy = py[ki], ccz = pz[ki];
    float bx = (float)(t / 9 - 1), by = (float)((t / 3) % 3 - 1), bz = (float)(t % 3 - 1);
    float vk0 = c0 + bx * 4.f, vk1 = c1 + by * 4.f, vk2 = c2 + bz * 4.f;
    float m0 = fminf(fmaxf(ccx - vk0, -1.f), 1.f) + vk0;
    float m1 = fminf(fmaxf(ccy - vk1, -1.f), 1.f) + vk1;
    float m2 = fminf(fmaxf(ccz - vk2, -1.f), 1.f) + vk2;
    mvx[t] = m0; mvy[t] = m1; mvz[t] = m2; oobs[t] = ob;
    float* vp = vox_in + ((size_t)n * 27 + t) * 4;
    vp[1] = m0; vp[2] = m1; vp[3] = m2;
  }
  __syncthreads();
  // idx_scatter: later bin overwrites, rep = |p - mv| <= r/2 per dim (r=2)
  int is = 27;
#pragma unroll 1
  for (int b = 0; b < 27; ++b) {
    if (!oobs[b] && fabsf(p0 - mvx[b]) <= 1.f && fabsf(p1 - mvy[b]) <= 1.f &&
        fabsf(p2 - mvz[b]) <= 1.f)
      is = b;
  }
  atomicAdd(&vadd[is], v);
  atomicAdd(&vcnt[is], 1);
  __syncthreads();
  if (t < 27) {
    float cnt = fmaxf((float)vcnt[t], 1.f);
    vox_in[((size_t)n * 27 + t) * 4 + 0] = vadd[t] / cnt;
  }
  if (t < 81) {
    float cnt = fminf(fmaxf(ccnt[t], 1.f), 8192.f);
    feats[(size_t)t * NPT + n] = cadd[t] / cnt;
  }
  // exact 32-NN among the K=128 by squared distance, rank = position (ties by index)
  float d = dd[t];
  int rank = 0;
  for (int j = 0; j < 128; ++j) {
    float dj = dd[j];
    rank += (dj < d || (dj == d && j < t)) ? 1 : 0;
  }
  if (rank < 32) {
    float* kp = knn_in + ((size_t)n * 32 + rank) * 4;
    *(float4*)kp = make_float4(v, dx, dy, dz);
  }
}

// ---------------- vox branch: conv(4->32) GN stats ----------------
__global__ __launch_bounds__(256) void k_vox_stats(const float* __restrict__ vox_in,
                                                   const float* __restrict__ w1,
                                                   const float* __restrict__ b1,
                                                   double* __restrict__ stats) {
  float gs[8], gq[8];
#pragma unroll
  for (int g = 0; g < 8; ++g) { gs[g] = 0.f; gq[g] = 0.f; }
  for (int s = blockIdx.x * 256 + threadIdx.x; s < NPT * 27; s += gridDim.x * 256) {
    float4 in = *(const float4*)(vox_in + (size_t)s * 4);
#pragma unroll
    for (int oc = 0; oc < 32; ++oc) {
      float4 w = *(const float4*)(w1 + oc * 4);
      float h = w.x * in.x + w.y * in.y + w.z * in.z + w.w * in.w + b1[oc];
      gs[oc >> 2] += h; gq[oc >> 2] += h * h;
    }
  }
  __shared__ float ls[8], lq[8];
  if (threadIdx.x < 8) { ls[threadIdx.x] = 0.f; lq[threadIdx.x] = 0.f; }
  __syncthreads();
#pragma unroll
  for (int g = 0; g < 8; ++g) { atomicAdd(&ls[g], gs[g]); atomicAdd(&lq[g], gq[g]); }
  __syncthreads();
  if (threadIdx.x < 8) {
    atomicAdd(&stats[threadIdx.x * 2 + 0], (double)ls[threadIdx.x]);
    atomicAdd(&stats[threadIdx.x * 2 + 1], (double)lq[threadIdx.x]);
  }
}

// ---------------- knn branch: conv(4->64) GN stats ----------------
__global__ __launch_bounds__(256) void k_knn_stats(const float* __restrict__ knn_in,
                                                   const float* __restrict__ w1,
                                                   const float* __restrict__ b1,
                                                   double* __restrict__ stats) {
  float gs[8], gq[8];
#pragma unroll
  for (int g = 0; g < 8; ++g) { gs[g] = 0.f; gq[g] = 0.f; }
  for (int s = blockIdx.x * 256 + threadIdx.x; s < NPT * 32; s += gridDim.x * 256) {
    float4 in = *(const float4*)(knn_in + (size_t)s * 4);
#pragma unroll
    for (int oc = 0; oc < 64; ++oc) {
      float4 w = *(const float4*)(w1 + oc * 4);
      float h = w.x * in.x + w.y * in.y + w.z * in.z + w.w * in.w + b1[oc];
      gs[oc >> 3] += h; gq[oc >> 3] += h * h;
    }
  }
  __shared__ float ls[8], lq[8];
  if (threadIdx.x < 8) { ls[threadIdx.x] = 0.f; lq[threadIdx.x] = 0.f; }
  __syncthreads();
#pragma unroll
  for (int g = 0; g < 8; ++g) { atomicAdd(&ls[g], gs[g]); atomicAdd(&lq[g], gq[g]); }
  __syncthreads();
  if (threadIdx.x < 8) {
    atomicAdd(&stats[threadIdx.x * 2 + 0], (double)ls[threadIdx.x]);
    atomicAdd(&stats[threadIdx.x * 2 + 1], (double)lq[threadIdx.x]);
  }
}

// ---------------- vox branch apply: GN+PReLU+conv(32->1) -> feats rows 81..107 ----------------
__global__ __launch_bounds__(256) void k_vox_apply(const float* __restrict__ vox_in,
                                                   const float* __restrict__ w1,
                                                   const float* __restrict__ b1,
                                                   const float* __restrict__ gamma,
                                                   const float* __restrict__ beta,
                                                   const float* __restrict__ pr,
                                                   const float* __restrict__ w2,
                                                   const float* __restrict__ b2,
                                                   const double* __restrict__ stats,
                                                   float* __restrict__ feats) {
  int s = blockIdx.x * 256 + threadIdx.x;
  if (s >= NPT * 27) return;
  float mean[8], rstd[8];
  const double cntd = 4.0 * 8192.0 * 27.0;
#pragma unroll
  for (int g = 0; g < 8; ++g) {
    double m = stats[2 * g] / cntd;
    double var = stats[2 * g + 1] / cntd - m * m;
    mean[g] = (float)m;
    rstd[g] = (float)(1.0 / sqrt(var + 1e-5));
  }
  float a = pr[0];
  float4 in = *(const float4*)(vox_in + (size_t)s * 4);
  float out = b2[0];
#pragma unroll
  for (int oc = 0; oc < 32; ++oc) {
    float4 w = *(const float4*)(w1 + oc * 4);
    float h = w.x * in.x + w.y * in.y + w.z * in.z + w.w * in.w + b1[oc];
    int g = oc >> 2;
    float xn = (h - mean[g]) * rstd[g] * gamma[oc] + beta[oc];
    float y = (xn >= 0.f) ? xn : a * xn;
    out += w2[oc] * y;
  }
  int n = s / 27, bb = s - n * 27;
  feats[(size_t)(81 + bb) * NPT + n] = out;
}

// ---------------- knn apply: GN+PReLU, max over 32 -> kf (64 x N) ----------------
__global__ __launch_bounds__(256) void k_knn_max(const float* __restrict__ knn_in,
                                                 const float* __restrict__ w1,
                                                 const float* __restrict__ b1,
                                                 const float* __restrict__ gamma,
                                                 const float* __restrict__ beta,
                                                 const float* __restrict__ pr,
                                                 const double* __restrict__ stats,
                                                 float* __restrict__ kf) {
  int tid0 = blockIdx.x * 256 + threadIdx.x;
  int n = tid0 & (NPT - 1);
  int oc = tid0 >> 13;
  const double cntd = 8.0 * 8192.0 * 32.0;
  int g = oc >> 3;
  double md = stats[2 * g] / cntd;
  double var = stats[2 * g + 1] / cntd - md * md;
  float mean = (float)md, rstd = (float)(1.0 / sqrt(var + 1e-5));
  float4 w = *(const float4*)(w1 + oc * 4);
  float bb = b1[oc], ga = gamma[oc], be = beta[oc], a = pr[0];
  float mx = -INFINITY;
  for (int j = 0; j < 32; ++j) {
    float4 in = *(const float4*)(knn_in + ((size_t)n * 32 + j) * 4);
    float h = w.x * in.x + w.y * in.y + w.z * in.z + w.w * in.w + bb;
    float xn = (h - mean) * rstd * ga + be;
    float y = (xn >= 0.f) ? xn : a * xn;
    mx = fmaxf(mx, y);
  }
  kf[(size_t)oc * NPT + n] = mx;
}

// ---------------- out branch conv1 (108->128) + GN stats ----------------
// block: 64 points; wave w computes ocs [w*32, w*32+32). 1 LDS read per ic,
// weights via wave-uniform s_loads, 32 register accumulators.
__global__ __launch_bounds__(256) void k_out1(const float* __restrict__ feats,
                                              const float* __restrict__ w1,
                                              const float* __restrict__ b1,
                                              float* __restrict__ h1,
                                              double* __restrict__ stats) {
  __shared__ float vf[108 * 64];
  __shared__ float ls[8], lq[8];
  int n0 = blockIdx.x * 64, tid = threadIdx.x;
  for (int i = tid; i < 108 * 64; i += 256) {
    int ch = i >> 6, nn = i & 63;
    vf[i] = feats[(size_t)ch * NPT + n0 + nn];
  }
  if (tid < 8) { ls[tid] = 0.f; lq[tid] = 0.f; }
  __syncthreads();
  int lane = tid & 63, wv = tid >> 6;
  int ocb = wv * 32;
  float acc[32];
#pragma unroll
  for (int j = 0; j < 32; ++j) acc[j] = b1[ocb + j];
#pragma unroll 2
  for (int ic = 0; ic < 108; ++ic) {
    float v = vf[ic * 64 + lane];
#pragma unroll
    for (int j = 0; j < 32; ++j) acc[j] += w1[(ocb + j) * 108 + ic] * v;
  }
  float g0 = 0.f, g1 = 0.f, q0 = 0.f, q1 = 0.f;
#pragma unroll
  for (int j = 0; j < 32; ++j) {
    h1[(size_t)(ocb + j) * NPT + n0 + lane] = acc[j];
    if (j < 16) { g0 += acc[j]; q0 += acc[j] * acc[j]; }
    else        { g1 += acc[j]; q1 += acc[j] * acc[j]; }
  }
  for (int off = 32; off; off >>= 1) {
    g0 += __shfl_down(g0, off); g1 += __shfl_down(g1, off);
    q0 += __shfl_down(q0, off); q1 += __shfl_down(q1, off);
  }
  if (lane == 0) {
    atomicAdd(&ls[wv * 2 + 0], g0); atomicAdd(&lq[wv * 2 + 0], q0);
    atomicAdd(&ls[wv * 2 + 1], g1); atomicAdd(&lq[wv * 2 + 1], q1);
  }
  __syncthreads();
  if (tid < 8) {
    atomicAdd(&stats[2 * tid + 0], (double)ls[tid]);
    atomicAdd(&stats[2 * tid + 1], (double)lq[tid]);
  }
}

// ---------------- final: GN+PReLU on h1, conv(128->64) + conv(64->64)(kf) ----------------
__global__ __launch_bounds__(256) void k_final(const float* __restrict__ h1,
                                               const float* __restrict__ kf,
                                               const float* __restrict__ gamma,
                                               const float* __restrict__ beta,
                                               const float* __restrict__ pr,
                                               const float* __restrict__ w2,
                                               const float* __restrict__ b2,
                                               const float* __restrict__ kow,
                                               const float* __restrict__ kob,
                                               const double* __restrict__ stats,
                                               float* __restrict__ out) {
  __shared__ float hn[128 * 64];
  __shared__ float kft[64 * 64];
  __shared__ float s_mean[8], s_rstd[8];
  int n0 = blockIdx.x * 64, tid = threadIdx.x;
  if (tid < 8) {
    const double cntd = 16.0 * 8192.0;
    double m = stats[2 * tid] / cntd;
    double var = stats[2 * tid + 1] / cntd - m * m;
    s_mean[tid] = (float)m;
    s_rstd[tid] = (float)(1.0 / sqrt(var + 1e-5));
  }
  __syncthreads();
  float a = pr[0];
  for (int i = tid; i < 128 * 64; i += 256) {
    int ch = i >> 6, nn = i & 63;
    int g = ch >> 4;
    float x = h1[(size_t)ch * NPT + n0 + nn];
    float xn = (x - s_mean[g]) * s_rstd[g] * gamma[ch] + beta[ch];
    hn[i] = (xn >= 0.f) ? xn : a * xn;
  }
  for (int i = tid; i < 64 * 64; i += 256) {
    int ch = i >> 6, nn = i & 63;
    kft[i] = kf[(size_t)ch * NPT + n0 + nn];
  }
  __syncthreads();
  int lane = tid & 63, wv = tid >> 6;
  int ocb = wv * 16;
  float acc[16];
#pragma unroll
  for (int j = 0; j < 16; ++j) acc[j] = b2[ocb + j] + kob[ocb + j];
#pragma unroll 2
  for (int ic = 0; ic < 128; ++ic) {
    float v = hn[ic * 64 + lane];
#pragma unroll
    for (int j = 0; j < 16; ++j) acc[j] += w2[(ocb + j) * 128 + ic] * v;
  }
#pragma unroll 2
  for (int ic = 0; ic < 64; ++ic) {
    float v = kft[ic * 64 + lane];
#pragma unroll
    for (int j = 0; j < 16; ++j) acc[j] += kow[(ocb + j) * 64 + ic] * v;
  }
#pragma unroll
  for (int j = 0; j < 16; ++j)
    out[(size_t)(ocb + j) * NPT + n0 + lane] = acc[j];
}

extern "C" void kernel_launch(void* const* d_in, const int* in_sizes, int n_in,
                              void* d_out, int out_size, void* d_ws, size_t ws_size,
                              hipStream_t stream) {
  (void)in_sizes; (void)n_in; (void)out_size;
  const float* fmap1  = (const float*)d_in[0];
  const float* fmap2  = (const float*)d_in[1];
  const float* xyz2   = (const float*)d_in[2];
  const float* coords = (const float*)d_in[3];
  const float* out_w1 = (const float*)d_in[4];
  const float* out_b1 = (const float*)d_in[5];
  const float* out_g  = (const float*)d_in[6];
  const float* out_bt = (const float*)d_in[7];
  const float* out_pr = (const float*)d_in[8];
  const float* out_w2 = (const float*)d_in[9];
  const float* out_b2 = (const float*)d_in[10];
  const float* vox_w1 = (const float*)d_in[11];
  const float* vox_b1 = (const float*)d_in[12];
  const float* vox_g  = (const float*)d_in[13];
  const float* vox_bt = (const float*)d_in[14];
  const float* vox_pr = (const float*)d_in[15];
  const float* vox_w2 = (const float*)d_in[16];
  const float* vox_b2 = (const float*)d_in[17];
  const float* knn_w1 = (const float*)d_in[18];
  const float* knn_b1 = (const float*)d_in[19];
  const float* knn_g  = (const float*)d_in[20];
  const float* knn_bt = (const float*)d_in[21];
  const float* knn_pr = (const float*)d_in[22];
  const float* knn_ow = (const float*)d_in[23];
  const float* knn_ob = (const float*)d_in[24];

  float* ws = (float*)d_ws;
  const size_t nonslab = 6488512ull;  // floats: tcorr+tidx+feats+vox_in+knn_in+h1+kf
  int SR;
  if (ws_size >= (8388608ull + nonslab) * 4ull + 512ull) SR = 1024;
  else if (ws_size >= (4194304ull + nonslab) * 4ull + 512ull) SR = 512;
  else SR = 256;

  float* slab   = ws;
  float* tcorr  = slab + (size_t)SR * NPT;
  int*   tidx   = (int*)(tcorr + (size_t)NPT * KK);
  float* feats  = tcorr + (size_t)NPT * KK * 2;
  float* vox_in = feats + 108 * NPT;
  float* knn_in = vox_in + (size_t)NPT * 27 * 4;
  float* h1     = knn_in + (size_t)NPT * 32 * 4;
  float* kf     = h1 + 128 * NPT;
  double* stats = (double*)(kf + 64 * NPT);

  hipLaunchKernelGGL(k_zero, dim3(1), dim3(64), 0, stream, stats);
  int iters = NPT / SR;
  for (int s = 0; s < iters; ++s) {
    hipLaunchKernelGGL(k_gemm, dim3(16, SR / 16), dim3(256), 0, stream, fmap1, fmap2, slab, s * SR);
    hipLaunchKernelGGL(k_select, dim3(SR), dim3(256), 0, stream, slab, s * SR, tcorr, tidx);
  }
  hipLaunchKernelGGL(k_point, dim3(NPT), dim3(128), 0, stream, tcorr, tidx, xyz2, coords,
                     feats, vox_in, knn_in);
  hipLaunchKernelGGL(k_vox_stats, dim3(256), dim3(256), 0, stream, vox_in, vox_w1, vox_b1, stats);
  hipLaunchKernelGGL(k_knn_stats, dim3(512), dim3(256), 0, stream, knn_in, knn_w1, knn_b1, stats + 16);
  hipLaunchKernelGGL(k_vox_apply, dim3((NPT * 27 + 255) / 256), dim3(256), 0, stream, vox_in,
                     vox_w1, vox_b1, vox_g, vox_bt, vox_pr, vox_w2, vox_b2, stats, feats);
  hipLaunchKernelGGL(k_knn_max, dim3(64 * NPT / 256), dim3(256), 0, stream, knn_in, knn_w1,
                     knn_b1, knn_g, knn_bt, knn_pr, stats + 16, kf);
  hipLaunchKernelGGL(k_out1, dim3(NPT / 64), dim3(256), 0, stream, feats, out_w1, out_b1, h1,
                     stats + 32);
  hipLaunchKernelGGL(k_final, dim3(NPT / 64), dim3(256), 0, stream, h1, kf, out_g, out_bt,
                     out_pr, out_w2, out_b2, knn_ow, knn_ob, stats + 32, (float*)d_out);
}

// Round 4
// 895.334 us; speedup vs baseline: 1.8634x; 1.1023x over previous
//
#include <hip/hip_runtime.h>
#include <math.h>

#define NPT 8192
#define CCH 128
#define KK  128

__device__ __forceinline__ unsigned f2key(float f) {
  unsigned u = __float_as_uint(f);
  return u ^ ((u & 0x80000000u) ? 0xFFFFFFFFu : 0x80000000u);
}
__device__ __forceinline__ float key2f(unsigned k) {
  unsigned u = (k & 0x80000000u) ? (k ^ 0x80000000u) : ~k;
  return __uint_as_float(u);
}

// ---------------- stats zero ----------------
__global__ void k_zero(double* s) {
  int t = threadIdx.x;
  if (t < 48) s[t] = 0.0;
}

// ---------------- corr GEMM (fp32, slab) ----------------
// grid (8, SR/16): block = 16 rows x 1024 cols, 4 cols/thread.
__global__ __launch_bounds__(256, 2) void k_gemm(const float* __restrict__ A,
                                                 const float* __restrict__ B,
                                                 float* __restrict__ slab, int row0) {
  __shared__ float a_s[CCH * 16];  // [c][r]
  int tid = threadIdx.x;
  int rbase = row0 + blockIdx.y * 16;
  for (int i = tid; i < CCH * 16; i += 256) {
    int c = i >> 4, r = i & 15;
    a_s[i] = A[(size_t)c * NPT + rbase + r];
  }
  __syncthreads();
  int m = blockIdx.x * 1024 + tid * 4;
  float acc[16][4];
#pragma unroll
  for (int r = 0; r < 16; ++r) { acc[r][0] = acc[r][1] = acc[r][2] = acc[r][3] = 0.f; }
#pragma unroll 2
  for (int c = 0; c < CCH; ++c) {
    float4 bv = *(const float4*)(B + (size_t)c * NPT + m);
    const float4* a4 = (const float4*)(a_s + c * 16);
#pragma unroll
    for (int q = 0; q < 4; ++q) {
      float4 av = a4[q];
      acc[q * 4 + 0][0] += av.x * bv.x; acc[q * 4 + 0][1] += av.x * bv.y;
      acc[q * 4 + 0][2] += av.x * bv.z; acc[q * 4 + 0][3] += av.x * bv.w;
      acc[q * 4 + 1][0] += av.y * bv.x; acc[q * 4 + 1][1] += av.y * bv.y;
      acc[q * 4 + 1][2] += av.y * bv.z; acc[q * 4 + 1][3] += av.y * bv.w;
      acc[q * 4 + 2][0] += av.z * bv.x; acc[q * 4 + 2][1] += av.z * bv.y;
      acc[q * 4 + 2][2] += av.z * bv.z; acc[q * 4 + 2][3] += av.z * bv.w;
      acc[q * 4 + 3][0] += av.w * bv.x; acc[q * 4 + 3][1] += av.w * bv.y;
      acc[q * 4 + 3][2] += av.w * bv.z; acc[q * 4 + 3][3] += av.w * bv.w;
    }
  }
  const float sc = 0.08838834764831845f;  // 1/sqrt(128)
  int rl = blockIdx.y * 16;
#pragma unroll
  for (int r = 0; r < 16; ++r) {
    float4 o = make_float4(acc[r][0] * sc, acc[r][1] * sc, acc[r][2] * sc, acc[r][3] * sc);
    *(float4*)(slab + (size_t)(rl + r) * NPT + m) = o;
  }
}

// ---------------- exact per-row top-128: bitwise binary search on keys ----------------
__global__ __launch_bounds__(256) void k_select(const float* __restrict__ slab, int row0,
                                                float* __restrict__ tcorr, int* __restrict__ tidx) {
  __shared__ int wcnt[4];
  __shared__ int sh_cnt;
  int tid = threadIdx.x, lane = tid & 63, wv = tid >> 6;
  const float* rowp = slab + (size_t)blockIdx.x * NPT;
  unsigned key[32];
#pragma unroll
  for (int j = 0; j < 32; ++j) key[j] = f2key(rowp[tid + j * 256]);
  if (tid == 0) sh_cnt = 0;
  unsigned P = 0;
  for (int b = 31; b >= 0; --b) {
    unsigned P1 = P | (1u << b);
    int c = 0;
#pragma unroll
    for (int j = 0; j < 32; ++j) c += (key[j] >= P1) ? 1 : 0;
    for (int off = 32; off; off >>= 1) c += __shfl_down(c, off);
    __syncthreads();  // protect wcnt from previous iteration's readers
    if (lane == 0) wcnt[wv] = c;
    __syncthreads();
    int tot = wcnt[0] + wcnt[1] + wcnt[2] + wcnt[3];
    if (tot >= KK) P = P1;
  }
  int row = row0 + blockIdx.x;
#pragma unroll
  for (int j = 0; j < 32; ++j) {
    if (key[j] > P) {
      int pos = atomicAdd(&sh_cnt, 1);
      tcorr[(size_t)row * KK + pos] = key2f(key[j]);
      tidx[(size_t)row * KK + pos] = tid + j * 256;
    }
  }
  __syncthreads();
#pragma unroll
  for (int j = 0; j < 32; ++j) {
    if (key[j] == P) {
      int pos = atomicAdd(&sh_cnt, 1);
      if (pos < KK) {
        tcorr[(size_t)row * KK + pos] = key2f(P);
        tidx[(size_t)row * KK + pos] = tid + j * 256;
      }
    }
  }
}

// ---------------- per-point voxel/coarse/knn geometry ----------------
__global__ __launch_bounds__(128) void k_point(const float* __restrict__ tcorr,
                                               const int* __restrict__ tidx,
                                               const float* __restrict__ xyz2,
                                               const float* __restrict__ coords,
                                               float* __restrict__ feats,
                                               float* __restrict__ vox_in,
                                               float* __restrict__ knn_in) {
  __shared__ float px[128], py[128], pz[128], dd[128];
  __shared__ float cadd[81], ccnt[81];
  __shared__ unsigned long long cmax[27];
  __shared__ unsigned long long gmax;  // block-wide argmax of corr (sorted position 0)
  __shared__ float mvx[27], mvy[27], mvz[27];
  __shared__ int oobs[27];
  __shared__ float vadd[28];
  __shared__ int vcnt[28];
  int n = blockIdx.x, t = threadIdx.x;
  float v = tcorr[(size_t)n * KK + t];
  int idx = tidx[(size_t)n * KK + t];
  float p0 = xyz2[idx * 3 + 0], p1 = xyz2[idx * 3 + 1], p2 = xyz2[idx * 3 + 2];
  float c0 = coords[n * 3 + 0], c1 = coords[n * 3 + 1], c2 = coords[n * 3 + 2];
  px[t] = p0; py[t] = p1; pz[t] = p2;
  float dx = p0 - c0, dy = p1 - c1, dz = p2 - c2;
  dd[t] = dx * dx + dy * dy + dz * dz;
  if (t < 81) { cadd[t] = 0.f; ccnt[t] = 0.f; }
  if (t < 27) cmax[t] = 0ULL;
  if (t < 28) { vadd[t] = 0.f; vcnt[t] = 0; }
  if (t == 0) gmax = 0ULL;
  __syncthreads();
#pragma unroll
  for (int lvl = 0; lvl < 3; ++lvl) {
    float rinv = (lvl == 0) ? 4.f : (lvl == 1) ? 2.f : 1.f;
    float d0 = rintf(dx * rinv), d1 = rintf(dy * rinv), d2 = rintf(dz * rinv);
    if (fabsf(d0) <= 1.f && fabsf(d1) <= 1.f && fabsf(d2) <= 1.f) {
      int cube = (int)(d0 + 1.f) * 9 + (int)(d1 + 1.f) * 3 + (int)(d2 + 1.f);
      atomicAdd(&cadd[lvl * 27 + cube], v);
      atomicAdd(&ccnt[lvl * 27 + cube], 1.f);
    }
  }
  unsigned long long pk = (((unsigned long long)f2key(v)) << 32) | (unsigned)t;
  atomicMax(&gmax, pk);
  {
    float d0 = rintf(dx * 0.25f), d1 = rintf(dy * 0.25f), d2 = rintf(dz * 0.25f);
    if (fabsf(d0) <= 1.5f && fabsf(d1) <= 1.5f && fabsf(d2) <= 1.5f) {
      int bin = (int)(d0 + 1.f) * 9 + (int)(d1 + 1.f) * 3 + (int)(d2 + 1.f);
      atomicMax(&cmax[bin], pk);
    }
  }
  __syncthreads();
  if (t < 27) {
    unsigned long long pkb = cmax[t];
    unsigned hi = (unsigned)(pkb >> 32);
    int ob = (hi <= 0x80000000u) ? 1 : 0;  // empty bin or max corr <= 0
    int ki = ob ? (int)(gmax & 0xFFFFFFFFULL) : (int)(pkb & 0xFFFFFFFFULL);
    float ccx = px[ki], ccy = py[ki], ccz = pz[ki];
    float bx = (float)(t / 9 - 1), by = (float)((t / 3) % 3 - 1), bz = (float)(t % 3 - 1);
    float vk0 = c0 + bx * 4.f, vk1 = c1 + by * 4.f, vk2 = c2 + bz * 4.f;
    float m0 = fminf(fmaxf(ccx - vk0, -1.f), 1.f) + vk0;
    float m1 = fminf(fmaxf(ccy - vk1, -1.f), 1.f) + vk1;
    float m2 = fminf(fmaxf(ccz - vk2, -1.f), 1.f) + vk2;
    mvx[t] = m0; mvy[t] = m1; mvz[t] = m2; oobs[t] = ob;
    float* vp = vox_in + ((size_t)n * 27 + t) * 4;
    vp[1] = m0; vp[2] = m1; vp[3] = m2;
  }
  __syncthreads();
  int is = 27;
#pragma unroll 1
  for (int b = 0; b < 27; ++b) {
    if (!oobs[b] && fabsf(p0 - mvx[b]) <= 1.f && fabsf(p1 - mvy[b]) <= 1.f &&
        fabsf(p2 - mvz[b]) <= 1.f)
      is = b;
  }
  atomicAdd(&vadd[is], v);
  atomicAdd(&vcnt[is], 1);
  __syncthreads();
  if (t < 27) {
    float cnt = fmaxf((float)vcnt[t], 1.f);
    vox_in[((size_t)n * 27 + t) * 4 + 0] = vadd[t] / cnt;
  }
  if (t < 81) {
    float cnt = fminf(fmaxf(ccnt[t], 1.f), 8192.f);
    feats[(size_t)t * NPT + n] = cadd[t] / cnt;
  }
  float d = dd[t];
  int rank = 0;
  for (int j = 0; j < 128; ++j) {
    float dj = dd[j];
    rank += (dj < d || (dj == d && j < t)) ? 1 : 0;
  }
  if (rank < 32) {
    float* kp = knn_in + ((size_t)n * 32 + rank) * 4;
    *(float4*)kp = make_float4(v, dx, dy, dz);
  }
}

// ---------------- vox branch: conv(4->32) GN stats ----------------
__global__ __launch_bounds__(256) void k_vox_stats(const float* __restrict__ vox_in,
                                                   const float* __restrict__ w1,
                                                   const float* __restrict__ b1,
                                                   double* __restrict__ stats) {
  float gs[8], gq[8];
#pragma unroll
  for (int g = 0; g < 8; ++g) { gs[g] = 0.f; gq[g] = 0.f; }
  for (int s = blockIdx.x * 256 + threadIdx.x; s < NPT * 27; s += gridDim.x * 256) {
    float4 in = *(const float4*)(vox_in + (size_t)s * 4);
#pragma unroll
    for (int oc = 0; oc < 32; ++oc) {
      float4 w = *(const float4*)(w1 + oc * 4);
      float h = w.x * in.x + w.y * in.y + w.z * in.z + w.w * in.w + b1[oc];
      gs[oc >> 2] += h; gq[oc >> 2] += h * h;
    }
  }
  __shared__ float ls[8], lq[8];
  if (threadIdx.x < 8) { ls[threadIdx.x] = 0.f; lq[threadIdx.x] = 0.f; }
  __syncthreads();
#pragma unroll
  for (int g = 0; g < 8; ++g) { atomicAdd(&ls[g], gs[g]); atomicAdd(&lq[g], gq[g]); }
  __syncthreads();
  if (threadIdx.x < 8) {
    atomicAdd(&stats[threadIdx.x * 2 + 0], (double)ls[threadIdx.x]);
    atomicAdd(&stats[threadIdx.x * 2 + 1], (double)lq[threadIdx.x]);
  }
}

// ---------------- knn branch: conv(4->64) GN stats ----------------
__global__ __launch_bounds__(256) void k_knn_stats(const float* __restrict__ knn_in,
                                                   const float* __restrict__ w1,
                                                   const float* __restrict__ b1,
                                                   double* __restrict__ stats) {
  float gs[8], gq[8];
#pragma unroll
  for (int g = 0; g < 8; ++g) { gs[g] = 0.f; gq[g] = 0.f; }
  for (int s = blockIdx.x * 256 + threadIdx.x; s < NPT * 32; s += gridDim.x * 256) {
    float4 in = *(const float4*)(knn_in + (size_t)s * 4);
#pragma unroll
    for (int oc = 0; oc < 64; ++oc) {
      float4 w = *(const float4*)(w1 + oc * 4);
      float h = w.x * in.x + w.y * in.y + w.z * in.z + w.w * in.w + b1[oc];
      gs[oc >> 3] += h; gq[oc >> 3] += h * h;
    }
  }
  __shared__ float ls[8], lq[8];
  if (threadIdx.x < 8) { ls[threadIdx.x] = 0.f; lq[threadIdx.x] = 0.f; }
  __syncthreads();
#pragma unroll
  for (int g = 0; g < 8; ++g) { atomicAdd(&ls[g], gs[g]); atomicAdd(&lq[g], gq[g]); }
  __syncthreads();
  if (threadIdx.x < 8) {
    atomicAdd(&stats[threadIdx.x * 2 + 0], (double)ls[threadIdx.x]);
    atomicAdd(&stats[threadIdx.x * 2 + 1], (double)lq[threadIdx.x]);
  }
}

// ---------------- vox branch apply ----------------
__global__ __launch_bounds__(256) void k_vox_apply(const float* __restrict__ vox_in,
                                                   const float* __restrict__ w1,
                                                   const float* __restrict__ b1,
                                                   const float* __restrict__ gamma,
                                                   const float* __restrict__ beta,
                                                   const float* __restrict__ pr,
                                                   const float* __restrict__ w2,
                                                   const float* __restrict__ b2,
                                                   const double* __restrict__ stats,
                                                   float* __restrict__ feats) {
  int s = blockIdx.x * 256 + threadIdx.x;
  if (s >= NPT * 27) return;
  float mean[8], rstd[8];
  const double cntd = 4.0 * 8192.0 * 27.0;
#pragma unroll
  for (int g = 0; g < 8; ++g) {
    double m = stats[2 * g] / cntd;
    double var = stats[2 * g + 1] / cntd - m * m;
    mean[g] = (float)m;
    rstd[g] = (float)(1.0 / sqrt(var + 1e-5));
  }
  float a = pr[0];
  float4 in = *(const float4*)(vox_in + (size_t)s * 4);
  float out = b2[0];
#pragma unroll
  for (int oc = 0; oc < 32; ++oc) {
    float4 w = *(const float4*)(w1 + oc * 4);
    float h = w.x * in.x + w.y * in.y + w.z * in.z + w.w * in.w + b1[oc];
    int g = oc >> 2;
    float xn = (h - mean[g]) * rstd[g] * gamma[oc] + beta[oc];
    float y = (xn >= 0.f) ? xn : a * xn;
    out += w2[oc] * y;
  }
  int n = s / 27, bb = s - n * 27;
  feats[(size_t)(81 + bb) * NPT + n] = out;
}

// ---------------- knn apply: GN+PReLU, max over 32 -> kf (64 x N) ----------------
__global__ __launch_bounds__(256) void k_knn_max(const float* __restrict__ knn_in,
                                                 const float* __restrict__ w1,
                                                 const float* __restrict__ b1,
                                                 const float* __restrict__ gamma,
                                                 const float* __restrict__ beta,
                                                 const float* __restrict__ pr,
                                                 const double* __restrict__ stats,
                                                 float* __restrict__ kf) {
  int tid0 = blockIdx.x * 256 + threadIdx.x;
  int n = tid0 & (NPT - 1);
  int oc = tid0 >> 13;
  const double cntd = 8.0 * 8192.0 * 32.0;
  int g = oc >> 3;
  double md = stats[2 * g] / cntd;
  double var = stats[2 * g + 1] / cntd - md * md;
  float mean = (float)md, rstd = (float)(1.0 / sqrt(var + 1e-5));
  float4 w = *(const float4*)(w1 + oc * 4);
  float bb = b1[oc], ga = gamma[oc], be = beta[oc], a = pr[0];
  float mx = -INFINITY;
  for (int j = 0; j < 32; ++j) {
    float4 in = *(const float4*)(knn_in + ((size_t)n * 32 + j) * 4);
    float h = w.x * in.x + w.y * in.y + w.z * in.z + w.w * in.w + bb;
    float xn = (h - mean) * rstd * ga + be;
    float y = (xn >= 0.f) ? xn : a * xn;
    mx = fmaxf(mx, y);
  }
  kf[(size_t)oc * NPT + n] = mx;
}

// ---------------- out branch conv1 (108->128) + GN stats ----------------
// grid (32, 8): x = 256-point tile, y = oc group of 16 (== GN group).
// Weights staged in LDS transposed [ic][16]; wave-uniform ds_read_b128.
__global__ __launch_bounds__(256) void k_out1(const float* __restrict__ feats,
                                              const float* __restrict__ w1,
                                              const float* __restrict__ b1,
                                              float* __restrict__ h1,
                                              double* __restrict__ stats) {
  __shared__ float wlds[108 * 16];
  __shared__ float ls, lq;
  int t = threadIdx.x;
  int ocb = blockIdx.y * 16;
  for (int i = t; i < 108 * 16; i += 256) {
    int j = i / 108, ic = i - j * 108;
    wlds[ic * 16 + j] = w1[ocb * 108 + i];
  }
  if (t == 0) { ls = 0.f; lq = 0.f; }
  __syncthreads();
  int n = blockIdx.x * 256 + t;
  float acc[16];
#pragma unroll
  for (int j = 0; j < 16; ++j) acc[j] = b1[ocb + j];
#pragma unroll 4
  for (int ic = 0; ic < 108; ++ic) {
    float v = feats[(size_t)ic * NPT + n];
    const float4* w4 = (const float4*)(wlds + ic * 16);
#pragma unroll
    for (int q = 0; q < 4; ++q) {
      float4 w = w4[q];
      acc[q * 4 + 0] += w.x * v; acc[q * 4 + 1] += w.y * v;
      acc[q * 4 + 2] += w.z * v; acc[q * 4 + 3] += w.w * v;
    }
  }
  float s = 0.f, q = 0.f;
#pragma unroll
  for (int j = 0; j < 16; ++j) {
    h1[(size_t)(ocb + j) * NPT + n] = acc[j];
    s += acc[j]; q += acc[j] * acc[j];
  }
  for (int off = 32; off; off >>= 1) { s += __shfl_down(s, off); q += __shfl_down(q, off); }
  if ((t & 63) == 0) { atomicAdd(&ls, s); atomicAdd(&lq, q); }
  __syncthreads();
  if (t == 0) {
    atomicAdd(&stats[2 * blockIdx.y + 0], (double)ls);
    atomicAdd(&stats[2 * blockIdx.y + 1], (double)lq);
  }
}

// ---------------- final: GN+PReLU on h1, conv(128->64) + conv(64->64)(kf) ----------------
// grid (32, 8): x = 256-point tile, y = oc group of 8.
__global__ __launch_bounds__(256) void k_final(const float* __restrict__ h1,
                                               const float* __restrict__ kf,
                                               const float* __restrict__ gamma,
                                               const float* __restrict__ beta,
                                               const float* __restrict__ pr,
                                               const float* __restrict__ w2,
                                               const float* __restrict__ b2,
                                               const float* __restrict__ kow,
                                               const float* __restrict__ kob,
                                               const double* __restrict__ stats,
                                               float* __restrict__ out) {
  __shared__ float wl[192 * 8];   // [ic][8]: ic<128 -> w2, 128+ic -> kow
  __shared__ float scl[128], sft[128];
  int t = threadIdx.x;
  int ocb = blockIdx.y * 8;
  for (int i = t; i < 128 * 8; i += 256) {
    int j = i >> 7, ic = i & 127;
    wl[ic * 8 + j] = w2[(ocb + j) * 128 + ic];
  }
  for (int i = t; i < 64 * 8; i += 256) {
    int j = i >> 6, ic = i & 63;
    wl[(128 + ic) * 8 + j] = kow[(ocb + j) * 64 + ic];
  }
  if (t < 128) {
    const double cntd = 16.0 * 8192.0;
    int g = t >> 4;
    double m = stats[2 * g] / cntd;
    double var = stats[2 * g + 1] / cntd - m * m;
    float rs = (float)(1.0 / sqrt(var + 1e-5));
    float ga = gamma[t];
    scl[t] = rs * ga;
    sft[t] = beta[t] - (float)m * rs * ga;
  }
  __syncthreads();
  int n = blockIdx.x * 256 + t;
  float a = pr[0];
  float acc[8];
#pragma unroll
  for (int j = 0; j < 8; ++j) acc[j] = b2[ocb + j] + kob[ocb + j];
#pragma unroll 2
  for (int ic = 0; ic < 128; ++ic) {
    float x = h1[(size_t)ic * NPT + n];
    float xn = x * scl[ic] + sft[ic];
    float y = (xn >= 0.f) ? xn : a * xn;
    const float4* w4 = (const float4*)(wl + ic * 8);
    float4 wa = w4[0], wb = w4[1];
    acc[0] += wa.x * y; acc[1] += wa.y * y; acc[2] += wa.z * y; acc[3] += wa.w * y;
    acc[4] += wb.x * y; acc[5] += wb.y * y; acc[6] += wb.z * y; acc[7] += wb.w * y;
  }
#pragma unroll 2
  for (int ic = 0; ic < 64; ++ic) {
    float y = kf[(size_t)ic * NPT + n];
    const float4* w4 = (const float4*)(wl + (128 + ic) * 8);
    float4 wa = w4[0], wb = w4[1];
    acc[0] += wa.x * y; acc[1] += wa.y * y; acc[2] += wa.z * y; acc[3] += wa.w * y;
    acc[4] += wb.x * y; acc[5] += wb.y * y; acc[6] += wb.z * y; acc[7] += wb.w * y;
  }
#pragma unroll
  for (int j = 0; j < 8; ++j)
    out[(size_t)(ocb + j) * NPT + n] = acc[j];
}

extern "C" void kernel_launch(void* const* d_in, const int* in_sizes, int n_in,
                              void* d_out, int out_size, void* d_ws, size_t ws_size,
                              hipStream_t stream) {
  (void)in_sizes; (void)n_in; (void)out_size;
  const float* fmap1  = (const float*)d_in[0];
  const float* fmap2  = (const float*)d_in[1];
  const float* xyz2   = (const float*)d_in[2];
  const float* coords = (const float*)d_in[3];
  const float* out_w1 = (const float*)d_in[4];
  const float* out_b1 = (const float*)d_in[5];
  const float* out_g  = (const float*)d_in[6];
  const float* out_bt = (const float*)d_in[7];
  const float* out_pr = (const float*)d_in[8];
  const float* out_w2 = (const float*)d_in[9];
  const float* out_b2 = (const float*)d_in[10];
  const float* vox_w1 = (const float*)d_in[11];
  const float* vox_b1 = (const float*)d_in[12];
  const float* vox_g  = (const float*)d_in[13];
  const float* vox_bt = (const float*)d_in[14];
  const float* vox_pr = (const float*)d_in[15];
  const float* vox_w2 = (const float*)d_in[16];
  const float* vox_b2 = (const float*)d_in[17];
  const float* knn_w1 = (const float*)d_in[18];
  const float* knn_b1 = (const float*)d_in[19];
  const float* knn_g  = (const float*)d_in[20];
  const float* knn_bt = (const float*)d_in[21];
  const float* knn_pr = (const float*)d_in[22];
  const float* knn_ow = (const float*)d_in[23];
  const float* knn_ob = (const float*)d_in[24];

  float* ws = (float*)d_ws;
  const size_t nonslab = 6488512ull;
  int SR;
  if (ws_size >= (8388608ull + nonslab) * 4ull + 512ull) SR = 1024;
  else if (ws_size >= (4194304ull + nonslab) * 4ull + 512ull) SR = 512;
  else SR = 256;

  float* slab   = ws;
  float* tcorr  = slab + (size_t)SR * NPT;
  int*   tidx   = (int*)(tcorr + (size_t)NPT * KK);
  float* feats  = tcorr + (size_t)NPT * KK * 2;
  float* vox_in = feats + 108 * NPT;
  float* knn_in = vox_in + (size_t)NPT * 27 * 4;
  float* h1     = knn_in + (size_t)NPT * 32 * 4;
  float* kf     = h1 + 128 * NPT;
  double* stats = (double*)(kf + 64 * NPT);

  hipLaunchKernelGGL(k_zero, dim3(1), dim3(64), 0, stream, stats);
  int iters = NPT / SR;
  for (int s = 0; s < iters; ++s) {
    hipLaunchKernelGGL(k_gemm, dim3(8, SR / 16), dim3(256), 0, stream, fmap1, fmap2, slab, s * SR);
    hipLaunchKernelGGL(k_select, dim3(SR), dim3(256), 0, stream, slab, s * SR, tcorr, tidx);
  }
  hipLaunchKernelGGL(k_point, dim3(NPT), dim3(128), 0, stream, tcorr, tidx, xyz2, coords,
                     feats, vox_in, knn_in);
  hipLaunchKernelGGL(k_vox_stats, dim3(256), dim3(256), 0, stream, vox_in, vox_w1, vox_b1, stats);
  hipLaunchKernelGGL(k_knn_stats, dim3(512), dim3(256), 0, stream, knn_in, knn_w1, knn_b1, stats + 16);
  hipLaunchKernelGGL(k_vox_apply, dim3((NPT * 27 + 255) / 256), dim3(256), 0, stream, vox_in,
                     vox_w1, vox_b1, vox_g, vox_bt, vox_pr, vox_w2, vox_b2, stats, feats);
  hipLaunchKernelGGL(k_knn_max, dim3(64 * NPT / 256), dim3(256), 0, stream, knn_in, knn_w1,
                     knn_b1, knn_g, knn_bt, knn_pr, stats + 16, kf);
  hipLaunchKernelGGL(k_out1, dim3(32, 8), dim3(256), 0, stream, feats, out_w1, out_b1, h1,
                     stats + 32);
  hipLaunchKernelGGL(k_final, dim3(32, 8), dim3(256), 0, stream, h1, kf, out_g, out_bt,
                     out_pr, out_w2, out_b2, knn_ow, knn_ob, stats + 32, (float*)d_out);
}

// Round 5
// 783.324 us; speedup vs baseline: 2.1299x; 1.1430x over previous
//
#include <hip/hip_runtime.h>
#include <math.h>

#define NPT 8192
#define CCH 128
#define KK  128

__device__ __forceinline__ unsigned f2key(float f) {
  unsigned u = __float_as_uint(f);
  return u ^ ((u & 0x80000000u) ? 0xFFFFFFFFu : 0x80000000u);
}
__device__ __forceinline__ float key2f(unsigned k) {
  unsigned u = (k & 0x80000000u) ? (k ^ 0x80000000u) : ~k;
  return __uint_as_float(u);
}

// ---------------- stats+moments zero ----------------
__global__ void k_zero(double* s) {
  int t = threadIdx.x;
  if (t < 76) s[t] = 0.0;  // 48 stats + 28 moments
}

// ---------------- corr GEMM (fp32, slab) ----------------
// grid (8, SR/16): block = 16 rows x 1024 cols, 4 cols/thread.
// 8-deep explicit B prefetch: 8 global_load_dwordx4 in flight per wave.
__global__ __launch_bounds__(256, 2) void k_gemm(const float* __restrict__ A,
                                                 const float* __restrict__ B,
                                                 float* __restrict__ slab, int row0) {
  __shared__ float a_s[CCH * 16];  // [c][r]
  int tid = threadIdx.x;
  int rbase = row0 + blockIdx.y * 16;
  for (int i = tid; i < CCH * 16; i += 256) {
    int c = i >> 4, r = i & 15;
    a_s[i] = A[(size_t)c * NPT + rbase + r];
  }
  __syncthreads();
  int m = blockIdx.x * 1024 + tid * 4;
  const float* Bp = B + m;
  float acc[16][4];
#pragma unroll
  for (int r = 0; r < 16; ++r) { acc[r][0] = acc[r][1] = acc[r][2] = acc[r][3] = 0.f; }
#pragma unroll 1
  for (int ct = 0; ct < CCH; ct += 8) {
    float4 bv[8];
#pragma unroll
    for (int j = 0; j < 8; ++j) bv[j] = *(const float4*)(Bp + (size_t)(ct + j) * NPT);
#pragma unroll
    for (int j = 0; j < 8; ++j) {
      const float4* a4 = (const float4*)(a_s + (ct + j) * 16);
#pragma unroll
      for (int q = 0; q < 4; ++q) {
        float4 av = a4[q];
        acc[q * 4 + 0][0] += av.x * bv[j].x; acc[q * 4 + 0][1] += av.x * bv[j].y;
        acc[q * 4 + 0][2] += av.x * bv[j].z; acc[q * 4 + 0][3] += av.x * bv[j].w;
        acc[q * 4 + 1][0] += av.y * bv[j].x; acc[q * 4 + 1][1] += av.y * bv[j].y;
        acc[q * 4 + 1][2] += av.y * bv[j].z; acc[q * 4 + 1][3] += av.y * bv[j].w;
        acc[q * 4 + 2][0] += av.z * bv[j].x; acc[q * 4 + 2][1] += av.z * bv[j].y;
        acc[q * 4 + 2][2] += av.z * bv[j].z; acc[q * 4 + 2][3] += av.z * bv[j].w;
        acc[q * 4 + 3][0] += av.w * bv[j].x; acc[q * 4 + 3][1] += av.w * bv[j].y;
        acc[q * 4 + 3][2] += av.w * bv[j].z; acc[q * 4 + 3][3] += av.w * bv[j].w;
      }
    }
  }
  const float sc = 0.08838834764831845f;  // 1/sqrt(128)
  int rl = blockIdx.y * 16;
#pragma unroll
  for (int r = 0; r < 16; ++r) {
    float4 o = make_float4(acc[r][0] * sc, acc[r][1] * sc, acc[r][2] * sc, acc[r][3] * sc);
    *(float4*)(slab + (size_t)(rl + r) * NPT + m) = o;
  }
}

// ---------------- exact per-row top-128: bitwise binary search on keys ----------------
__global__ __launch_bounds__(256) void k_select(const float* __restrict__ slab, int row0,
                                                float* __restrict__ tcorr, int* __restrict__ tidx) {
  __shared__ int wcnt[4];
  __shared__ int sh_cnt;
  int tid = threadIdx.x, lane = tid & 63, wv = tid >> 6;
  const float* rowp = slab + (size_t)blockIdx.x * NPT;
  unsigned key[32];
#pragma unroll
  for (int j = 0; j < 32; ++j) key[j] = f2key(rowp[tid + j * 256]);
  if (tid == 0) sh_cnt = 0;
  unsigned P = 0;
  for (int b = 31; b >= 0; --b) {
    unsigned P1 = P | (1u << b);
    int c = 0;
#pragma unroll
    for (int j = 0; j < 32; ++j) c += (key[j] >= P1) ? 1 : 0;
    for (int off = 32; off; off >>= 1) c += __shfl_down(c, off);
    __syncthreads();
    if (lane == 0) wcnt[wv] = c;
    __syncthreads();
    int tot = wcnt[0] + wcnt[1] + wcnt[2] + wcnt[3];
    if (tot >= KK) P = P1;
  }
  int row = row0 + blockIdx.x;
#pragma unroll
  for (int j = 0; j < 32; ++j) {
    if (key[j] > P) {
      int pos = atomicAdd(&sh_cnt, 1);
      tcorr[(size_t)row * KK + pos] = key2f(key[j]);
      tidx[(size_t)row * KK + pos] = tid + j * 256;
    }
  }
  __syncthreads();
#pragma unroll
  for (int j = 0; j < 32; ++j) {
    if (key[j] == P) {
      int pos = atomicAdd(&sh_cnt, 1);
      if (pos < KK) {
        tcorr[(size_t)row * KK + pos] = key2f(P);
        tidx[(size_t)row * KK + pos] = tid + j * 256;
      }
    }
  }
}

// ---------------- per-point voxel/coarse/knn geometry ----------------
__global__ __launch_bounds__(128) void k_point(const float* __restrict__ tcorr,
                                               const int* __restrict__ tidx,
                                               const float* __restrict__ xyz2,
                                               const float* __restrict__ coords,
                                               float* __restrict__ feats,
                                               float* __restrict__ vox_in,
                                               float* __restrict__ knn_in) {
  __shared__ float px[128], py[128], pz[128], dd[128];
  __shared__ float cadd[81], ccnt[81];
  __shared__ unsigned long long cmax[27];
  __shared__ unsigned long long gmax;
  __shared__ float mvx[27], mvy[27], mvz[27];
  __shared__ int oobs[27];
  __shared__ float vadd[28];
  __shared__ int vcnt[28];
  int n = blockIdx.x, t = threadIdx.x;
  float v = tcorr[(size_t)n * KK + t];
  int idx = tidx[(size_t)n * KK + t];
  float p0 = xyz2[idx * 3 + 0], p1 = xyz2[idx * 3 + 1], p2 = xyz2[idx * 3 + 2];
  float c0 = coords[n * 3 + 0], c1 = coords[n * 3 + 1], c2 = coords[n * 3 + 2];
  px[t] = p0; py[t] = p1; pz[t] = p2;
  float dx = p0 - c0, dy = p1 - c1, dz = p2 - c2;
  dd[t] = dx * dx + dy * dy + dz * dz;
  if (t < 81) { cadd[t] = 0.f; ccnt[t] = 0.f; }
  if (t < 27) cmax[t] = 0ULL;
  if (t < 28) { vadd[t] = 0.f; vcnt[t] = 0; }
  if (t == 0) gmax = 0ULL;
  __syncthreads();
#pragma unroll
  for (int lvl = 0; lvl < 3; ++lvl) {
    float rinv = (lvl == 0) ? 4.f : (lvl == 1) ? 2.f : 1.f;
    float d0 = rintf(dx * rinv), d1 = rintf(dy * rinv), d2 = rintf(dz * rinv);
    if (fabsf(d0) <= 1.f && fabsf(d1) <= 1.f && fabsf(d2) <= 1.f) {
      int cube = (int)(d0 + 1.f) * 9 + (int)(d1 + 1.f) * 3 + (int)(d2 + 1.f);
      atomicAdd(&cadd[lvl * 27 + cube], v);
      atomicAdd(&ccnt[lvl * 27 + cube], 1.f);
    }
  }
  unsigned long long pk = (((unsigned long long)f2key(v)) << 32) | (unsigned)t;
  atomicMax(&gmax, pk);
  {
    float d0 = rintf(dx * 0.25f), d1 = rintf(dy * 0.25f), d2 = rintf(dz * 0.25f);
    if (fabsf(d0) <= 1.5f && fabsf(d1) <= 1.5f && fabsf(d2) <= 1.5f) {
      int bin = (int)(d0 + 1.f) * 9 + (int)(d1 + 1.f) * 3 + (int)(d2 + 1.f);
      atomicMax(&cmax[bin], pk);
    }
  }
  __syncthreads();
  if (t < 27) {
    unsigned long long pkb = cmax[t];
    unsigned hi = (unsigned)(pkb >> 32);
    int ob = (hi <= 0x80000000u) ? 1 : 0;
    int ki = ob ? (int)(gmax & 0xFFFFFFFFULL) : (int)(pkb & 0xFFFFFFFFULL);
    float ccx = px[ki], ccy = py[ki], ccz = pz[ki];
    float bx = (float)(t / 9 - 1), by = (float)((t / 3) % 3 - 1), bz = (float)(t % 3 - 1);
    float vk0 = c0 + bx * 4.f, vk1 = c1 + by * 4.f, vk2 = c2 + bz * 4.f;
    float m0 = fminf(fmaxf(ccx - vk0, -1.f), 1.f) + vk0;
    float m1 = fminf(fmaxf(ccy - vk1, -1.f), 1.f) + vk1;
    float m2 = fminf(fmaxf(ccz - vk2, -1.f), 1.f) + vk2;
    mvx[t] = m0; mvy[t] = m1; mvz[t] = m2; oobs[t] = ob;
    float* vp = vox_in + ((size_t)n * 27 + t) * 4;
    vp[1] = m0; vp[2] = m1; vp[3] = m2;
  }
  __syncthreads();
  int is = 27;
#pragma unroll 1
  for (int b = 0; b < 27; ++b) {
    if (!oobs[b] && fabsf(p0 - mvx[b]) <= 1.f && fabsf(p1 - mvy[b]) <= 1.f &&
        fabsf(p2 - mvz[b]) <= 1.f)
      is = b;
  }
  atomicAdd(&vadd[is], v);
  atomicAdd(&vcnt[is], 1);
  __syncthreads();
  if (t < 27) {
    float cnt = fmaxf((float)vcnt[t], 1.f);
    vox_in[((size_t)n * 27 + t) * 4 + 0] = vadd[t] / cnt;
  }
  if (t < 81) {
    float cnt = fminf(fmaxf(ccnt[t], 1.f), 8192.f);
    feats[(size_t)t * NPT + n] = cadd[t] / cnt;
  }
  float d = dd[t];
  int rank = 0;
  for (int j = 0; j < 128; ++j) {
    float dj = dd[j];
    rank += (dj < d || (dj == d && j < t)) ? 1 : 0;
  }
  if (rank < 32) {
    float* kp = knn_in + ((size_t)n * 32 + rank) * 4;
    *(float4*)kp = make_float4(v, dx, dy, dz);
  }
}

// ---------------- input moments for GN stats (conv is linear) ----------------
// mom[0..13]: vox S[4],M[10];  mom[14..27]: knn S[4],M[10]
__global__ __launch_bounds__(256) void k_moments(const float* __restrict__ vox_in,
                                                 const float* __restrict__ knn_in,
                                                 double* __restrict__ mom) {
  int b = blockIdx.x, t = threadIdx.x;
  int isknn = (b >= 256) ? 1 : 0;
  const float* src = isknn ? knn_in : vox_in;
  int nsite = isknn ? NPT * 32 : NPT * 27;
  int base = isknn ? 14 : 0;
  int bb = isknn ? b - 256 : b;
  float S0 = 0, S1 = 0, S2 = 0, S3 = 0;
  float M00 = 0, M01 = 0, M02 = 0, M03 = 0, M11 = 0, M12 = 0, M13 = 0, M22 = 0, M23 = 0, M33 = 0;
  for (int s = bb * 256 + t; s < nsite; s += 256 * 256) {
    float4 x = *(const float4*)(src + (size_t)s * 4);
    S0 += x.x; S1 += x.y; S2 += x.z; S3 += x.w;
    M00 += x.x * x.x; M01 += x.x * x.y; M02 += x.x * x.z; M03 += x.x * x.w;
    M11 += x.y * x.y; M12 += x.y * x.z; M13 += x.y * x.w;
    M22 += x.z * x.z; M23 += x.z * x.w; M33 += x.w * x.w;
  }
  float vals[14] = {S0, S1, S2, S3, M00, M01, M02, M03, M11, M12, M13, M22, M23, M33};
  for (int off = 32; off; off >>= 1)
#pragma unroll
    for (int i = 0; i < 14; ++i) vals[i] += __shfl_down(vals[i], off);
  __shared__ float part[14];
  if (t < 14) part[t] = 0.f;
  __syncthreads();
  if ((t & 63) == 0)
#pragma unroll
    for (int i = 0; i < 14; ++i) atomicAdd(&part[i], vals[i]);
  __syncthreads();
  if (t < 14) atomicAdd(&mom[base + t], (double)part[t]);
}

// ---------------- finalize GN stats from moments ----------------
// stats[0..15] vox groups (sum,sumsq), stats[16..31] knn groups
__global__ void k_stats_fin(const float* __restrict__ vw1, const float* __restrict__ vb1,
                            const float* __restrict__ kw1, const float* __restrict__ kb1,
                            const double* __restrict__ mom, double* __restrict__ stats) {
  int t = threadIdx.x;
  if (t >= 16) return;
  int isknn = (t >= 8) ? 1 : 0;
  const double* m = mom + (isknn ? 14 : 0);
  const float* W = isknn ? kw1 : vw1;
  const float* Bi = isknn ? kb1 : vb1;
  double N = isknn ? (double)NPT * 32.0 : (double)NPT * 27.0;
  int per = isknn ? 8 : 4;
  int g = isknn ? t - 8 : t;
  double S0 = m[0], S1 = m[1], S2 = m[2], S3 = m[3];
  double M00 = m[4], M01 = m[5], M02 = m[6], M03 = m[7];
  double M11 = m[8], M12 = m[9], M13 = m[10], M22 = m[11], M23 = m[12], M33 = m[13];
  double sum = 0.0, ssq = 0.0;
  for (int k = 0; k < per; ++k) {
    int oc = g * per + k;
    double w0 = W[oc * 4 + 0], w1 = W[oc * 4 + 1], w2 = W[oc * 4 + 2], w3 = W[oc * 4 + 3];
    double b = Bi[oc];
    double ws = w0 * S0 + w1 * S1 + w2 * S2 + w3 * S3;
    double q = w0 * w0 * M00 + w1 * w1 * M11 + w2 * w2 * M22 + w3 * w3 * M33 +
               2.0 * (w0 * w1 * M01 + w0 * w2 * M02 + w0 * w3 * M03 +
                      w1 * w2 * M12 + w1 * w3 * M13 + w2 * w3 * M23);
    sum += ws + N * b;
    ssq += q + 2.0 * b * ws + N * b * b;
  }
  double* out = stats + (isknn ? 16 : 0);
  out[2 * g + 0] = sum;
  out[2 * g + 1] = ssq;
}

// ---------------- vox branch apply ----------------
__global__ __launch_bounds__(256) void k_vox_apply(const float* __restrict__ vox_in,
                                                   const float* __restrict__ w1,
                                                   const float* __restrict__ b1,
                                                   const float* __restrict__ gamma,
                                                   const float* __restrict__ beta,
                                                   const float* __restrict__ pr,
                                                   const float* __restrict__ w2,
                                                   const float* __restrict__ b2,
                                                   const double* __restrict__ stats,
                                                   float* __restrict__ feats) {
  int s = blockIdx.x * 256 + threadIdx.x;
  if (s >= NPT * 27) return;
  float mean[8], rstd[8];
  const double cntd = 4.0 * 8192.0 * 27.0;
#pragma unroll
  for (int g = 0; g < 8; ++g) {
    double m = stats[2 * g] / cntd;
    double var = stats[2 * g + 1] / cntd - m * m;
    mean[g] = (float)m;
    rstd[g] = (float)(1.0 / sqrt(var + 1e-5));
  }
  float a = pr[0];
  float4 in = *(const float4*)(vox_in + (size_t)s * 4);
  float out = b2[0];
#pragma unroll
  for (int oc = 0; oc < 32; ++oc) {
    float4 w = *(const float4*)(w1 + oc * 4);
    float h = w.x * in.x + w.y * in.y + w.z * in.z + w.w * in.w + b1[oc];
    int g = oc >> 2;
    float xn = (h - mean[g]) * rstd[g] * gamma[oc] + beta[oc];
    float y = (xn >= 0.f) ? xn : a * xn;
    out += w2[oc] * y;
  }
  int n = s / 27, bb = s - n * 27;
  feats[(size_t)(81 + bb) * NPT + n] = out;
}

// ---------------- knn apply: GN+PReLU, max over 32 -> kf (64 x N) ----------------
__global__ __launch_bounds__(256) void k_knn_max(const float* __restrict__ knn_in,
                                                 const float* __restrict__ w1,
                                                 const float* __restrict__ b1,
                                                 const float* __restrict__ gamma,
                                                 const float* __restrict__ beta,
                                                 const float* __restrict__ pr,
                                                 const double* __restrict__ stats,
                                                 float* __restrict__ kf) {
  int tid0 = blockIdx.x * 256 + threadIdx.x;
  int n = tid0 & (NPT - 1);
  int oc = tid0 >> 13;
  const double cntd = 8.0 * 8192.0 * 32.0;
  int g = oc >> 3;
  double md = stats[2 * g] / cntd;
  double var = stats[2 * g + 1] / cntd - md * md;
  float mean = (float)md, rstd = (float)(1.0 / sqrt(var + 1e-5));
  float4 w = *(const float4*)(w1 + oc * 4);
  float bb = b1[oc], ga = gamma[oc], be = beta[oc], a = pr[0];
  float mx = -INFINITY;
  for (int j = 0; j < 32; ++j) {
    float4 in = *(const float4*)(knn_in + ((size_t)n * 32 + j) * 4);
    float h = w.x * in.x + w.y * in.y + w.z * in.z + w.w * in.w + bb;
    float xn = (h - mean) * rstd * ga + be;
    float y = (xn >= 0.f) ? xn : a * xn;
    mx = fmaxf(mx, y);
  }
  kf[(size_t)oc * NPT + n] = mx;
}

// ---------------- out branch conv1 (108->128) + GN stats ----------------
__global__ __launch_bounds__(256) void k_out1(const float* __restrict__ feats,
                                              const float* __restrict__ w1,
                                              const float* __restrict__ b1,
                                              float* __restrict__ h1,
                                              double* __restrict__ stats) {
  __shared__ float wlds[108 * 16];
  __shared__ float ls, lq;
  int t = threadIdx.x;
  int ocb = blockIdx.y * 16;
  for (int i = t; i < 108 * 16; i += 256) {
    int j = i / 108, ic = i - j * 108;
    wlds[ic * 16 + j] = w1[ocb * 108 + i];
  }
  if (t == 0) { ls = 0.f; lq = 0.f; }
  __syncthreads();
  int n = blockIdx.x * 256 + t;
  float acc[16];
#pragma unroll
  for (int j = 0; j < 16; ++j) acc[j] = b1[ocb + j];
#pragma unroll 4
  for (int ic = 0; ic < 108; ++ic) {
    float v = feats[(size_t)ic * NPT + n];
    const float4* w4 = (const float4*)(wlds + ic * 16);
#pragma unroll
    for (int q = 0; q < 4; ++q) {
      float4 w = w4[q];
      acc[q * 4 + 0] += w.x * v; acc[q * 4 + 1] += w.y * v;
      acc[q * 4 + 2] += w.z * v; acc[q * 4 + 3] += w.w * v;
    }
  }
  float s = 0.f, q = 0.f;
#pragma unroll
  for (int j = 0; j < 16; ++j) {
    h1[(size_t)(ocb + j) * NPT + n] = acc[j];
    s += acc[j]; q += acc[j] * acc[j];
  }
  for (int off = 32; off; off >>= 1) { s += __shfl_down(s, off); q += __shfl_down(q, off); }
  if ((t & 63) == 0) { atomicAdd(&ls, s); atomicAdd(&lq, q); }
  __syncthreads();
  if (t == 0) {
    atomicAdd(&stats[2 * blockIdx.y + 0], (double)ls);
    atomicAdd(&stats[2 * blockIdx.y + 1], (double)lq);
  }
}

// ---------------- final: GN+PReLU on h1, conv(128->64) + conv(64->64)(kf) ----------------
__global__ __launch_bounds__(256) void k_final(const float* __restrict__ h1,
                                               const float* __restrict__ kf,
                                               const float* __restrict__ gamma,
                                               const float* __restrict__ beta,
                                               const float* __restrict__ pr,
                                               const float* __restrict__ w2,
                                               const float* __restrict__ b2,
                                               const float* __restrict__ kow,
                                               const float* __restrict__ kob,
                                               const double* __restrict__ stats,
                                               float* __restrict__ out) {
  __shared__ float wl[192 * 8];
  __shared__ float scl[128], sft[128];
  int t = threadIdx.x;
  int ocb = blockIdx.y * 8;
  for (int i = t; i < 128 * 8; i += 256) {
    int j = i >> 7, ic = i & 127;
    wl[ic * 8 + j] = w2[(ocb + j) * 128 + ic];
  }
  for (int i = t; i < 64 * 8; i += 256) {
    int j = i >> 6, ic = i & 63;
    wl[(128 + ic) * 8 + j] = kow[(ocb + j) * 64 + ic];
  }
  if (t < 128) {
    const double cntd = 16.0 * 8192.0;
    int g = t >> 4;
    double m = stats[2 * g] / cntd;
    double var = stats[2 * g + 1] / cntd - m * m;
    float rs = (float)(1.0 / sqrt(var + 1e-5));
    float ga = gamma[t];
    scl[t] = rs * ga;
    sft[t] = beta[t] - (float)m * rs * ga;
  }
  __syncthreads();
  int n = blockIdx.x * 256 + t;
  float a = pr[0];
  float acc[8];
#pragma unroll
  for (int j = 0; j < 8; ++j) acc[j] = b2[ocb + j] + kob[ocb + j];
#pragma unroll 2
  for (int ic = 0; ic < 128; ++ic) {
    float x = h1[(size_t)ic * NPT + n];
    float xn = x * scl[ic] + sft[ic];
    float y = (xn >= 0.f) ? xn : a * xn;
    const float4* w4 = (const float4*)(wl + ic * 8);
    float4 wa = w4[0], wb = w4[1];
    acc[0] += wa.x * y; acc[1] += wa.y * y; acc[2] += wa.z * y; acc[3] += wa.w * y;
    acc[4] += wb.x * y; acc[5] += wb.y * y; acc[6] += wb.z * y; acc[7] += wb.w * y;
  }
#pragma unroll 2
  for (int ic = 0; ic < 64; ++ic) {
    float y = kf[(size_t)ic * NPT + n];
    const float4* w4 = (const float4*)(wl + (128 + ic) * 8);
    float4 wa = w4[0], wb = w4[1];
    acc[0] += wa.x * y; acc[1] += wa.y * y; acc[2] += wa.z * y; acc[3] += wa.w * y;
    acc[4] += wb.x * y; acc[5] += wb.y * y; acc[6] += wb.z * y; acc[7] += wb.w * y;
  }
#pragma unroll
  for (int j = 0; j < 8; ++j)
    out[(size_t)(ocb + j) * NPT + n] = acc[j];
}

extern "C" void kernel_launch(void* const* d_in, const int* in_sizes, int n_in,
                              void* d_out, int out_size, void* d_ws, size_t ws_size,
                              hipStream_t stream) {
  (void)in_sizes; (void)n_in; (void)out_size;
  const float* fmap1  = (const float*)d_in[0];
  const float* fmap2  = (const float*)d_in[1];
  const float* xyz2   = (const float*)d_in[2];
  const float* coords = (const float*)d_in[3];
  const float* out_w1 = (const float*)d_in[4];
  const float* out_b1 = (const float*)d_in[5];
  const float* out_g  = (const float*)d_in[6];
  const float* out_bt = (const float*)d_in[7];
  const float* out_pr = (const float*)d_in[8];
  const float* out_w2 = (const float*)d_in[9];
  const float* out_b2 = (const float*)d_in[10];
  const float* vox_w1 = (const float*)d_in[11];
  const float* vox_b1 = (const float*)d_in[12];
  const float* vox_g  = (const float*)d_in[13];
  const float* vox_bt = (const float*)d_in[14];
  const float* vox_pr = (const float*)d_in[15];
  const float* vox_w2 = (const float*)d_in[16];
  const float* vox_b2 = (const float*)d_in[17];
  const float* knn_w1 = (const float*)d_in[18];
  const float* knn_b1 = (const float*)d_in[19];
  const float* knn_g  = (const float*)d_in[20];
  const float* knn_bt = (const float*)d_in[21];
  const float* knn_pr = (const float*)d_in[22];
  const float* knn_ow = (const float*)d_in[23];
  const float* knn_ob = (const float*)d_in[24];

  float* ws = (float*)d_ws;
  const size_t nonslab = 6488064ull;
  int SR;
  if (ws_size >= (8388608ull + nonslab) * 4ull + 1024ull) SR = 1024;
  else if (ws_size >= (4194304ull + nonslab) * 4ull + 1024ull) SR = 512;
  else SR = 256;

  float* slab   = ws;
  float* tcorr  = slab + (size_t)SR * NPT;
  int*   tidx   = (int*)(tcorr + (size_t)NPT * KK);
  float* feats  = tcorr + (size_t)NPT * KK * 2;
  float* vox_in = feats + 108 * NPT;
  float* knn_in = vox_in + (size_t)NPT * 27 * 4;
  float* h1     = knn_in + (size_t)NPT * 32 * 4;
  float* kf     = h1 + 128 * NPT;
  double* stats = (double*)(kf + 64 * NPT);
  double* mom   = stats + 48;

  hipLaunchKernelGGL(k_zero, dim3(1), dim3(128), 0, stream, stats);
  int iters = NPT / SR;
  for (int s = 0; s < iters; ++s) {
    hipLaunchKernelGGL(k_gemm, dim3(8, SR / 16), dim3(256), 0, stream, fmap1, fmap2, slab, s * SR);
    hipLaunchKernelGGL(k_select, dim3(SR), dim3(256), 0, stream, slab, s * SR, tcorr, tidx);
  }
  hipLaunchKernelGGL(k_point, dim3(NPT), dim3(128), 0, stream, tcorr, tidx, xyz2, coords,
                     feats, vox_in, knn_in);
  hipLaunchKernelGGL(k_moments, dim3(512), dim3(256), 0, stream, vox_in, knn_in, mom);
  hipLaunchKernelGGL(k_stats_fin, dim3(1), dim3(64), 0, stream, vox_w1, vox_b1, knn_w1, knn_b1,
                     mom, stats);
  hipLaunchKernelGGL(k_vox_apply, dim3((NPT * 27 + 255) / 256), dim3(256), 0, stream, vox_in,
                     vox_w1, vox_b1, vox_g, vox_bt, vox_pr, vox_w2, vox_b2, stats, feats);
  hipLaunchKernelGGL(k_knn_max, dim3(64 * NPT / 256), dim3(256), 0, stream, knn_in, knn_w1,
                     knn_b1, knn_g, knn_bt, knn_pr, stats + 16, kf);
  hipLaunchKernelGGL(k_out1, dim3(32, 8), dim3(256), 0, stream, feats, out_w1, out_b1, h1,
                     stats + 32);
  hipLaunchKernelGGL(k_final, dim3(32, 8), dim3(256), 0, stream, h1, kf, out_g, out_bt,
                     out_pr, out_w2, out_b2, knn_ow, knn_ob, stats + 32, (float*)d_out);
}